// Round 1
// baseline (3951.738 us; speedup 1.0000x reference)
//
#include <hip/hip_runtime.h>

// ---- problem constants ----
#define BB 64      // batch
#define TE 40      // encoder steps
#define TD 40      // decoder steps
#define ED 300     // embedding dim
#define EP 320     // padded embedding dim (mult of 32)
#define HD 896     // hidden
#define G3 2688    // 3*H
#define VO 30000   // vocab out
#define VP 30080   // padded vocab (235*128)
#define KZ 1792    // 2*H
#define MR 2560    // T*B rows

typedef __attribute__((ext_vector_type(8))) __bf16 bf16x8;
typedef __attribute__((ext_vector_type(4))) float f32x4;
typedef __attribute__((ext_vector_type(4))) unsigned int u32x4;

__device__ __forceinline__ float sig_(float x)  { return 1.0f / (1.0f + __expf(-x)); }
__device__ __forceinline__ float tanh_(float x) { return 1.0f - 2.0f / (__expf(2.0f * x) + 1.0f); }

// ---------------------------------------------------------------------------
// Generic bf16 MFMA GEMM, C = A @ B^T (+bias). A:[M,K], B:[N,K], both row-major
// K-contiguous ("BT" layout). 256 threads = 4 waves, wave grid WGM x WGN.
// MODE 0: C[M][N] fp32 (+bias if non-null)
// MODE 1: FC epilogue -> out[b*TD*VO + t*VO + col] with row=t*64+b, col<Nreal
// Dual pointer set selected by blockIdx.z (lets encoder fwd+bwd share a launch).
// ---------------------------------------------------------------------------
template<int BM, int BN, int WGM, int WGN, int MODE>
__global__ __launch_bounds__(256) void gemm_bt(
    const __bf16* __restrict__ A0, const __bf16* __restrict__ B0,
    float* __restrict__ C0, const float* __restrict__ bias0,
    const __bf16* __restrict__ A1, const __bf16* __restrict__ B1,
    float* __restrict__ C1, const float* __restrict__ bias1,
    int M, int N, int K, int Nreal)
{
    constexpr int BK = 32, PAD = 8;
    constexpr int WM = BM / WGM, WN = BN / WGN;
    constexpr int FM = WM / 16, FN = WN / 16;
    constexpr int LDS_W = BK + PAD;   // 40 bf16 = 80B row stride (16B aligned)

    const __bf16* A = A0; const __bf16* Bp = B0;
    float* C = C0; const float* bias = bias0;
    if (blockIdx.z == 1) { A = A1; Bp = B1; C = C1; bias = bias1; }

    __shared__ __bf16 Ash[BM][LDS_W];
    __shared__ __bf16 Bsh[BN][LDS_W];

    const int tid  = threadIdx.x;
    const int lane = tid & 63;
    const int wave = tid >> 6;
    const int wr = wave / WGN, wc = wave % WGN;
    const long tileM = (long)blockIdx.y * BM;
    const long tileN = (long)blockIdx.x * BN;

    const int r16 = lane & 15;   // A row / B col / D col within 16-frag
    const int hi  = lane >> 4;   // 0..3: k-group for A/B, row-group for D

    f32x4 acc[FM][FN];
    const f32x4 zero = {0.f, 0.f, 0.f, 0.f};
#pragma unroll
    for (int m = 0; m < FM; ++m)
#pragma unroll
        for (int n = 0; n < FN; ++n) acc[m][n] = zero;

    for (int k0 = 0; k0 < K; k0 += BK) {
        // stage A tile [BM x 32] and B tile [BN x 32] (bf16, 16B per thread-chunk)
#pragma unroll
        for (int it = 0; it < (BM * 4) / 256; ++it) {
            int id = it * 256 + tid;
            int r = id >> 2, cv = (id & 3) << 3;
            *(u32x4*)&Ash[r][cv] = *(const u32x4*)&A[(tileM + r) * K + k0 + cv];
        }
#pragma unroll
        for (int it = 0; it < (BN * 4) / 256; ++it) {
            int id = it * 256 + tid;
            int r = id >> 2, cv = (id & 3) << 3;
            *(u32x4*)&Bsh[r][cv] = *(const u32x4*)&Bp[(tileN + r) * K + k0 + cv];
        }
        __syncthreads();

        // fragment layout (16x16x32): A[i][k]: i=lane&15, k=(lane>>4)*8+j ; B same
        bf16x8 af[FM], bfr[FN];
#pragma unroll
        for (int m = 0; m < FM; ++m)
            af[m] = *(const bf16x8*)&Ash[wr * WM + m * 16 + r16][hi * 8];
#pragma unroll
        for (int n = 0; n < FN; ++n)
            bfr[n] = *(const bf16x8*)&Bsh[wc * WN + n * 16 + r16][hi * 8];
#pragma unroll
        for (int m = 0; m < FM; ++m)
#pragma unroll
            for (int n = 0; n < FN; ++n)
                acc[m][n] = __builtin_amdgcn_mfma_f32_16x16x32_bf16(af[m], bfr[n], acc[m][n], 0, 0, 0);
        __syncthreads();
    }

    // D layout (verified): col = lane&15, row = (lane>>4)*4 + reg
#pragma unroll
    for (int m = 0; m < FM; ++m) {
#pragma unroll
        for (int n = 0; n < FN; ++n) {
            const long gcol = tileN + wc * WN + n * 16 + r16;
            if (MODE == 1 && gcol >= Nreal) continue;
            const float bv = bias ? bias[gcol] : 0.0f;
#pragma unroll
            for (int r = 0; r < 4; ++r) {
                const long grow = tileM + wr * WM + m * 16 + hi * 4 + r;
                const float v = acc[m][n][r] + bv;
                if (MODE == 0) {
                    C[grow * N + gcol] = v;
                } else {
                    const long t = grow >> 6, b = grow & 63;
                    C[(b * TD + t) * VO + gcol] = v;
                }
            }
        }
    }
}

// fp32 -> bf16 convert with optional row/col zero-padding
__global__ __launch_bounds__(256) void conv_pad(const float* __restrict__ src,
                                                __bf16* __restrict__ dst,
                                                int Rout, int Rin, int Kout, int Kin)
{
    size_t i = (size_t)blockIdx.x * 256 + threadIdx.x;
    const size_t total = (size_t)Rout * Kout;
    const size_t stride = (size_t)gridDim.x * 256;
    for (; i < total; i += stride) {
        int k = (int)(i % Kout);
        int r = (int)(i / Kout);
        float v = (r < Rin && k < Kin) ? src[(size_t)r * Kin + k] : 0.0f;
        dst[i] = (__bf16)v;
    }
}

// gather token embeddings into padded bf16 matrix X[(t*B+b)][EP]
__global__ __launch_bounds__(256) void gather_embed(const int* __restrict__ tok,
                                                    const float* __restrict__ emb,
                                                    __bf16* __restrict__ X)
{
    int i = blockIdx.x * 256 + threadIdx.x;
    const int total = TE * BB * EP;
    for (; i < total; i += gridDim.x * 256) {
        int e = i % EP;
        int row = i / EP;
        int t = row >> 6, b = row & 63;
        float v = 0.0f;
        if (e < ED) v = emb[(size_t)tok[b * TE + t] * ED + e];
        X[i] = (__bf16)v;
    }
}

// encoder GRU gates, both directions in one launch (blockIdx.z = dir)
__global__ __launch_bounds__(256) void enc_gates(
    const float* __restrict__ GIf, const float* __restrict__ GHf,
    const float* __restrict__ bhhF, float* __restrict__ hf, __bf16* __restrict__ hfb,
    const float* __restrict__ GIb, const float* __restrict__ GHb,
    const float* __restrict__ bhhB, float* __restrict__ hb, __bf16* __restrict__ hbb,
    float* __restrict__ yenc, int t)
{
    const int i = blockIdx.x * 256 + threadIdx.x;   // exactly B*H threads
    const int b = i / HD, c = i % HD;
    const float* GI; const float* GH; const float* bhh; float* h; __bf16* hbf; int tt;
    if (blockIdx.z == 0) { GI = GIf; GH = GHf; bhh = bhhF; h = hf; hbf = hfb; tt = t; }
    else                 { GI = GIb; GH = GHb; bhh = bhhB; h = hb; hbf = hbb; tt = TE - 1 - t; }

    const size_t gi = ((size_t)tt * BB + b) * G3;
    const size_t gh = (size_t)b * G3;
    float r = sig_(GI[gi + c]           + GH[gh + c]           + bhh[c]);
    float z = sig_(GI[gi + HD + c]      + GH[gh + HD + c]      + bhh[HD + c]);
    float n = tanh_(GI[gi + 2 * HD + c] + r * (GH[gh + 2 * HD + c] + bhh[2 * HD + c]));
    float hnew = (1.0f - z) * n + z * h[i];
    h[i] = hnew;
    hbf[i] = (__bf16)hnew;
    yenc[((size_t)b * TE + tt) * HD + c] += hnew;  // fwd slot t, bwd slot TE-1-t (disjoint)
}

// decoder GRU gates; writes h2 (fp32 for attention, bf16 for next GEMM + Z row)
__global__ __launch_bounds__(256) void dec_gates(
    const float* __restrict__ GI, const float* __restrict__ GH,
    const float* __restrict__ bhh, float* __restrict__ h, __bf16* __restrict__ hbf,
    __bf16* __restrict__ Z, int s)
{
    const int i = blockIdx.x * 256 + threadIdx.x;
    const int b = i / HD, c = i % HD;
    const size_t gi = ((size_t)s * BB + b) * G3;
    const size_t gh = (size_t)b * G3;
    float r = sig_(GI[gi + c]           + GH[gh + c]           + bhh[c]);
    float z = sig_(GI[gi + HD + c]      + GH[gh + HD + c]      + bhh[HD + c]);
    float n = tanh_(GI[gi + 2 * HD + c] + r * (GH[gh + 2 * HD + c] + bhh[2 * HD + c]));
    float hnew = (1.0f - z) * n + z * h[i];
    h[i] = hnew;
    hbf[i] = (__bf16)hnew;
    Z[((size_t)s * BB + b) * KZ + c] = (__bf16)hnew;
}

__global__ __launch_bounds__(256) void hd_init(const float* __restrict__ hf,
                                               const float* __restrict__ hb,
                                               float* __restrict__ hd,
                                               __bf16* __restrict__ hdb)
{
    const int i = blockIdx.x * 256 + threadIdx.x;
    float v = hf[i] + hb[i];
    hd[i] = v;
    hdb[i] = (__bf16)v;
}

// dot-product attention for decoder step s: one block per batch element
__global__ __launch_bounds__(256) void attn_kernel(const float* __restrict__ yenc,
                                                   const float* __restrict__ h2,
                                                   __bf16* __restrict__ Z, int s)
{
    const int b = blockIdx.x;
    const int tid = threadIdx.x;
    __shared__ float h2s[HD];
    __shared__ float sc[TE];
    __shared__ float attw[TE];
    __shared__ float red[4];

    for (int c = tid; c < HD; c += 256) h2s[c] = h2[b * HD + c];
    __syncthreads();

    const float* ye = yenc + (size_t)b * TE * HD;
    for (int t = 0; t < TE; ++t) {
        float p = 0.0f;
        const float* yt = ye + t * HD;
        for (int c = tid; c < HD; c += 256) p += yt[c] * h2s[c];
        p += __shfl_down(p, 32); p += __shfl_down(p, 16); p += __shfl_down(p, 8);
        p += __shfl_down(p, 4);  p += __shfl_down(p, 2);  p += __shfl_down(p, 1);
        if ((tid & 63) == 0) red[tid >> 6] = p;
        __syncthreads();
        if (tid == 0) sc[t] = red[0] + red[1] + red[2] + red[3];
        __syncthreads();
    }
    if (tid == 0) {
        float m = sc[0];
        for (int t = 1; t < TE; ++t) m = fmaxf(m, sc[t]);
        float ssum = 0.0f;
        for (int t = 0; t < TE; ++t) { float e = __expf(sc[t] - m); attw[t] = e; ssum += e; }
        float inv = 1.0f / ssum;
        for (int t = 0; t < TE; ++t) attw[t] *= inv;
    }
    __syncthreads();
    for (int c = tid; c < HD; c += 256) {
        float acc = 0.0f;
#pragma unroll
        for (int t = 0; t < TE; ++t) acc += attw[t] * ye[t * HD + c];
        Z[((size_t)s * BB + b) * KZ + HD + c] = (__bf16)acc;
    }
}

// in-place row softmax over d_out rows of VO floats
__global__ __launch_bounds__(256) void softmax_kernel(float* __restrict__ out)
{
    const size_t base = (size_t)blockIdx.x * VO;
    const int tid = threadIdx.x;
    __shared__ float red[4];
    __shared__ float red2[4];

    float m = -1e30f;
    for (int v = tid; v < VO; v += 256) m = fmaxf(m, out[base + v]);
    m = fmaxf(m, __shfl_down(m, 32)); m = fmaxf(m, __shfl_down(m, 16));
    m = fmaxf(m, __shfl_down(m, 8));  m = fmaxf(m, __shfl_down(m, 4));
    m = fmaxf(m, __shfl_down(m, 2));  m = fmaxf(m, __shfl_down(m, 1));
    if ((tid & 63) == 0) red[tid >> 6] = m;
    __syncthreads();
    m = fmaxf(fmaxf(red[0], red[1]), fmaxf(red[2], red[3]));

    float s = 0.0f;
    for (int v = tid; v < VO; v += 256) s += __expf(out[base + v] - m);
    s += __shfl_down(s, 32); s += __shfl_down(s, 16); s += __shfl_down(s, 8);
    s += __shfl_down(s, 4);  s += __shfl_down(s, 2);  s += __shfl_down(s, 1);
    if ((tid & 63) == 0) red2[tid >> 6] = s;
    __syncthreads();
    s = red2[0] + red2[1] + red2[2] + red2[3];

    const float inv = 1.0f / s;
    for (int v = tid; v < VO; v += 256) out[base + v] = __expf(out[base + v] - m) * inv;
}

extern "C" void kernel_launch(void* const* d_in, const int* in_sizes, int n_in,
                              void* d_out, int out_size, void* d_ws, size_t ws_size,
                              hipStream_t stream)
{
    if (n_in < 18) return;
    const int*   x_enc   = (const int*)d_in[0];
    const int*   x_dec   = (const int*)d_in[1];
    const float* emb_enc = (const float*)d_in[2];
    const float* Wih_f   = (const float*)d_in[3];
    const float* Whh_f   = (const float*)d_in[4];
    const float* bih_f   = (const float*)d_in[5];
    const float* bhh_f   = (const float*)d_in[6];
    const float* Wih_b   = (const float*)d_in[7];
    const float* Whh_b   = (const float*)d_in[8];
    const float* bih_b   = (const float*)d_in[9];
    const float* bhh_b   = (const float*)d_in[10];
    const float* emb_dec = (const float*)d_in[11];
    const float* Wih_d   = (const float*)d_in[12];
    const float* Whh_d   = (const float*)d_in[13];
    const float* bih_d   = (const float*)d_in[14];
    const float* bhh_d   = (const float*)d_in[15];
    const float* fc_W    = (const float*)d_in[16];
    const float* fc_b    = (const float*)d_in[17];
    float* out = (float*)d_out;

    size_t off = 0;
    auto alloc = [&](size_t bytes) -> void* {
        void* p = (char*)d_ws + off;
        off = (off + bytes + 255) & ~(size_t)255;
        return p;
    };
    __bf16* fcWb  = (__bf16*)alloc((size_t)VP * KZ * 2);
    __bf16* WihFb = (__bf16*)alloc((size_t)G3 * EP * 2);
    __bf16* WihBb = (__bf16*)alloc((size_t)G3 * EP * 2);
    __bf16* WihDb = (__bf16*)alloc((size_t)G3 * EP * 2);
    __bf16* WhhFb = (__bf16*)alloc((size_t)G3 * HD * 2);
    __bf16* WhhBb = (__bf16*)alloc((size_t)G3 * HD * 2);
    __bf16* WhhDb = (__bf16*)alloc((size_t)G3 * HD * 2);
    __bf16* Xe    = (__bf16*)alloc((size_t)MR * EP * 2);
    __bf16* Xd    = (__bf16*)alloc((size_t)MR * EP * 2);
    float*  GIf   = (float*)alloc((size_t)MR * G3 * 4);
    float*  GIb   = (float*)alloc((size_t)MR * G3 * 4);
    float*  GId   = (float*)alloc((size_t)MR * G3 * 4);
    float*  GHf   = (float*)alloc((size_t)BB * G3 * 4);
    float*  GHb   = (float*)alloc((size_t)BB * G3 * 4);
    float*  GHd   = (float*)alloc((size_t)BB * G3 * 4);
    __bf16* Zb    = (__bf16*)alloc((size_t)MR * KZ * 2);
    char* zero_start = (char*)d_ws + off;
    float*  yenc  = (float*)alloc((size_t)BB * TE * HD * 4);
    float*  hf    = (float*)alloc((size_t)BB * HD * 4);
    float*  hb    = (float*)alloc((size_t)BB * HD * 4);
    __bf16* hfb   = (__bf16*)alloc((size_t)BB * HD * 2);
    __bf16* hbb   = (__bf16*)alloc((size_t)BB * HD * 2);
    size_t zero_bytes = (size_t)(((char*)d_ws + off) - zero_start);
    float*  hd    = (float*)alloc((size_t)BB * HD * 4);
    __bf16* hdb   = (__bf16*)alloc((size_t)BB * HD * 2);
    if (off > ws_size) return;   // ~235 MB required; fail visibly (zero output)

    // ---- init + weight conversion ----
    hipMemsetAsync(zero_start, 0, zero_bytes, stream);
    conv_pad<<<8192, 256, 0, stream>>>(fc_W,  fcWb,  VP, VO, KZ, KZ);
    conv_pad<<<3360, 256, 0, stream>>>(Wih_f, WihFb, G3, G3, EP, ED);
    conv_pad<<<3360, 256, 0, stream>>>(Wih_b, WihBb, G3, G3, EP, ED);
    conv_pad<<<3360, 256, 0, stream>>>(Wih_d, WihDb, G3, G3, EP, ED);
    conv_pad<<<9408, 256, 0, stream>>>(Whh_f, WhhFb, G3, G3, HD, HD);
    conv_pad<<<9408, 256, 0, stream>>>(Whh_b, WhhBb, G3, G3, HD, HD);
    conv_pad<<<9408, 256, 0, stream>>>(Whh_d, WhhDb, G3, G3, HD, HD);
    gather_embed<<<3200, 256, 0, stream>>>(x_enc, emb_enc, Xe);
    gather_embed<<<3200, 256, 0, stream>>>(x_dec, emb_dec, Xd);

    // ---- batched input-side GEMMs: GI = X @ Wih^T + bih ----
    gemm_bt<128, 128, 2, 2, 0><<<dim3(G3 / 128, MR / 128, 2), 256, 0, stream>>>(
        Xe, WihFb, GIf, bih_f, Xe, WihBb, GIb, bih_b, MR, G3, EP, G3);
    gemm_bt<128, 128, 2, 2, 0><<<dim3(G3 / 128, MR / 128, 1), 256, 0, stream>>>(
        Xd, WihDb, GId, bih_d, nullptr, nullptr, nullptr, nullptr, MR, G3, EP, G3);

    // ---- encoder: 40 sequential steps, fwd+bwd fused per launch ----
    for (int t = 0; t < TE; ++t) {
        gemm_bt<64, 128, 1, 4, 0><<<dim3(G3 / 128, 1, 2), 256, 0, stream>>>(
            hfb, WhhFb, GHf, nullptr, hbb, WhhBb, GHb, nullptr, BB, G3, HD, G3);
        enc_gates<<<dim3(BB * HD / 256, 1, 2), 256, 0, stream>>>(
            GIf, GHf, bhh_f, hf, hfb, GIb, GHb, bhh_b, hb, hbb, yenc, t);
    }
    hd_init<<<BB * HD / 256, 256, 0, stream>>>(hf, hb, hd, hdb);

    // ---- decoder: 40 sequential steps (GRU + attention) ----
    for (int s = 0; s < TD; ++s) {
        gemm_bt<64, 128, 1, 4, 0><<<dim3(G3 / 128, 1, 1), 256, 0, stream>>>(
            hdb, WhhDb, GHd, nullptr, nullptr, nullptr, nullptr, nullptr, BB, G3, HD, G3);
        dec_gates<<<BB * HD / 256, 256, 0, stream>>>(GId, GHd, bhh_d, hd, hdb, Zb, s);
        attn_kernel<<<BB, 256, 0, stream>>>(yenc, hd, Zb, s);
    }

    // ---- batched FC: logits = Z @ fc_W^T + fc_b, written straight into d_out ----
    gemm_bt<128, 128, 2, 2, 1><<<dim3(VP / 128, MR / 128, 1), 256, 0, stream>>>(
        Zb, fcWb, out, fc_b, nullptr, nullptr, nullptr, nullptr, MR, VP, KZ, VO);

    // ---- in-place row softmax ----
    softmax_kernel<<<BB * TD, 256, 0, stream>>>(out);
}

// Round 2
// 2263.303 us; speedup vs baseline: 1.7460x; 1.7460x over previous
//
#include <hip/hip_runtime.h>

// ---- problem constants ----
#define BB 64      // batch
#define TE 40      // encoder steps
#define TD 40      // decoder steps
#define ED 300     // embedding dim
#define EP 320     // padded embedding dim (mult of 32)
#define HD 896     // hidden
#define G3 2688    // 3*H
#define VO 30000   // vocab out
#define VP 30080   // padded vocab (235*128)
#define KZ 1792    // 2*H
#define MR 2560    // T*B rows
#define NBLK 120   // persistent-kernel grid (<=256 CUs, 1 block/CU by LDS)

typedef __attribute__((ext_vector_type(8))) __bf16 bf16x8;
typedef __attribute__((ext_vector_type(4))) float f32x4;
typedef __attribute__((ext_vector_type(4))) unsigned int u32x4;

__device__ __forceinline__ float sig_(float x)  { return 1.0f / (1.0f + __expf(-x)); }
__device__ __forceinline__ float tanh_(float x) { return 1.0f - 2.0f / (__expf(2.0f * x) + 1.0f); }

// ---------------------------------------------------------------------------
// Device-scope grid barrier: monotonic counter, no reset race.
// All NBLK blocks co-resident (1 block/CU, NBLK < 256 CUs).
// ---------------------------------------------------------------------------
__device__ __forceinline__ void gridbar(int* cnt, int target)
{
    __syncthreads();
    if (threadIdx.x == 0) {
        __hip_atomic_fetch_add(cnt, 1, __ATOMIC_ACQ_REL, __HIP_MEMORY_SCOPE_AGENT);
        while (__hip_atomic_load(cnt, __ATOMIC_ACQUIRE, __HIP_MEMORY_SCOPE_AGENT) < target)
            __builtin_amdgcn_s_sleep(2);
    }
    __syncthreads();
}

// stage 48 Whh rows (gates r,z,n at 16 c-values) fp32 -> bf16 LDS [48][904]
__device__ __forceinline__ void stage_w(__bf16* wlds, const float* __restrict__ W, int c0)
{
    const int tid = threadIdx.x;
    for (int ch = tid; ch < 48 * 224; ch += 256) {
        const int lr = ch / 224, col = (ch % 224) * 4;
        const int g = lr >> 4, r = lr & 15;
        const float4 v = *(const float4*)&W[(size_t)(g * HD + c0 + r) * HD + col];
        __bf16* d = &wlds[lr * 904 + col];
        d[0] = (__bf16)v.x; d[1] = (__bf16)v.y; d[2] = (__bf16)v.z; d[3] = (__bf16)v.w;
    }
}

// One GRU step for this block's 16 c-values, all 64 batch rows.
// wave w = m-frag (rows 16w..16w+15); 3 n-frags = the 3 gates at cols c0..c0+15.
// D-layout: lane holds (b = 16w + hi*4 + reg, c = c0 + r16) for all 3 gates.
__device__ __forceinline__ void gru_step(
    const __bf16* __restrict__ hcurB, const float* __restrict__ hcurF,
    const __bf16* __restrict__ wlds,
    const float* __restrict__ GIt,      // GI + step*BB*G3
    const float* __restrict__ bhh,
    float* __restrict__ hnF, __bf16* __restrict__ hnB,
    float* __restrict__ yenc_tt,        // yenc + tt*HD (encoder) or nullptr
    __bf16* __restrict__ zrow,          // Zb + s*BB*KZ (decoder) or nullptr
    int c0)
{
    const int tid = threadIdx.x;
    const int lane = tid & 63, w = tid >> 6;
    const int r16 = lane & 15, hi = lane >> 4;

    f32x4 acc0 = {0.f, 0.f, 0.f, 0.f}, acc1 = acc0, acc2 = acc0;
    const __bf16* ap = hcurB + (16 * w + r16) * HD + hi * 8;
    const __bf16* b0 = wlds + (0 * 16 + r16) * 904 + hi * 8;
    const __bf16* b1 = wlds + (1 * 16 + r16) * 904 + hi * 8;
    const __bf16* b2 = wlds + (2 * 16 + r16) * 904 + hi * 8;
#pragma unroll
    for (int kk = 0; kk < HD / 32; ++kk) {
        const bf16x8 a = *(const bf16x8*)(ap + kk * 32);
        acc0 = __builtin_amdgcn_mfma_f32_16x16x32_bf16(a, *(const bf16x8*)(b0 + kk * 32), acc0, 0, 0, 0);
        acc1 = __builtin_amdgcn_mfma_f32_16x16x32_bf16(a, *(const bf16x8*)(b1 + kk * 32), acc1, 0, 0, 0);
        acc2 = __builtin_amdgcn_mfma_f32_16x16x32_bf16(a, *(const bf16x8*)(b2 + kk * 32), acc2, 0, 0, 0);
    }
    const int c = c0 + r16;
    const float bh0 = bhh[c], bh1 = bhh[HD + c], bh2 = bhh[2 * HD + c];
#pragma unroll
    for (int rg = 0; rg < 4; ++rg) {
        const int b = 16 * w + hi * 4 + rg;
        const float* gi = GIt + (size_t)b * G3 + c;
        const float rr = sig_(gi[0]      + acc0[rg] + bh0);
        const float zz = sig_(gi[HD]     + acc1[rg] + bh1);
        const float nn = tanh_(gi[2 * HD] + rr * (acc2[rg] + bh2));
        const float hnew = (1.0f - zz) * nn + zz * hcurF[b * HD + c];
        hnF[b * HD + c] = hnew;
        hnB[b * HD + c] = (__bf16)hnew;
        if (yenc_tt) yenc_tt[(size_t)b * TE * HD + c] += hnew;
        if (zrow)    zrow[(size_t)b * KZ + c] = (__bf16)hnew;
    }
}

// attention for one batch element b (yenc[b] resident in LDS)
__device__ __forceinline__ void attn_step(
    const float* __restrict__ yencL, float* __restrict__ h2s,
    float* __restrict__ scL, float* __restrict__ attwL,
    const float* __restrict__ h2g, int b, __bf16* __restrict__ zr)
{
    const int tid = threadIdx.x, lane = tid & 63, w = tid >> 6;
    for (int c = tid; c < HD; c += 256) h2s[c] = h2g[(size_t)b * HD + c];
    __syncthreads();
    for (int t = w; t < TE; t += 4) {
        float p = 0.f;
        for (int j = lane; j < HD; j += 64) p += yencL[t * HD + j] * h2s[j];
        p += __shfl_down(p, 32); p += __shfl_down(p, 16); p += __shfl_down(p, 8);
        p += __shfl_down(p, 4);  p += __shfl_down(p, 2);  p += __shfl_down(p, 1);
        if (lane == 0) scL[t] = p;
    }
    __syncthreads();
    float m = scL[0];
    for (int t = 1; t < TE; ++t) m = fmaxf(m, scL[t]);
    float s = 0.f;
    for (int t = 0; t < TE; ++t) s += __expf(scL[t] - m);
    const float inv = 1.0f / s;
    if (tid < TE) attwL[tid] = __expf(scL[tid] - m) * inv;
    __syncthreads();
    for (int c = tid; c < HD; c += 256) {
        float a = 0.f;
#pragma unroll
        for (int t = 0; t < TE; ++t) a += attwL[t] * yencL[t * HD + c];
        zr[(size_t)b * KZ + HD + c] = (__bf16)a;
    }
}

// ---------------------------------------------------------------------------
// Persistent recurrence kernel: encoder (40 phases) + transition + decoder (41).
// blocks 0..55: GRU fwd (enc) / GRU dec; 56..111: GRU bwd (enc) / attn; 112..119: attn only.
// ---------------------------------------------------------------------------
__global__ __launch_bounds__(256) void recur(
    const float* __restrict__ GIf, const float* __restrict__ GIb,
    const float* __restrict__ GId,
    const float* __restrict__ WhhF, const float* __restrict__ WhhB,
    const float* __restrict__ WhhD,
    const float* __restrict__ bhhF, const float* __restrict__ bhhB,
    const float* __restrict__ bhhD,
    float* __restrict__ heF, __bf16* __restrict__ heB,   // [dir][buf][BB*HD]
    float* __restrict__ hdF, __bf16* __restrict__ hdB,   // [buf][BB*HD]
    float* __restrict__ yenc, __bf16* __restrict__ Zb,
    int* __restrict__ bar)
{
    __shared__ __align__(16) char smem[147264];
    __bf16* wlds  = (__bf16*)smem;                 // gru role: [48][904] bf16 (86,784 B)
    float*  yencL = (float*)smem;                  // attn role: [40][896] f32 (143,360 B)
    float*  h2s   = (float*)(smem + 143360);       // [896] f32
    float*  scL   = (float*)(smem + 146944);       // [40]
    float*  attwL = (float*)(smem + 147104);       // [40]

    const int gid = blockIdx.x;
    const int tid = threadIdx.x;
    const size_t S = (size_t)BB * HD;
    int ph = 0;

    // ---- encoder ----
    const bool eGru = gid < 112;
    const int dir = (gid >= 56) ? 1 : 0;
    const int c0e = (dir ? gid - 56 : gid) * 16;
    if (eGru) stage_w(wlds, dir ? WhhB : WhhF, c0e);
    __syncthreads();

    for (int t = 0; t < TE; ++t) {
        if (eGru) {
            const int tt = dir ? (TE - 1 - t) : t;
            const int cur = t & 1, nxt = cur ^ 1;
            gru_step(heB + (dir * 2 + cur) * S, heF + (dir * 2 + cur) * S, wlds,
                     (dir ? GIb : GIf) + (size_t)tt * BB * G3,
                     dir ? bhhB : bhhF,
                     heF + (dir * 2 + nxt) * S, heB + (dir * 2 + nxt) * S,
                     yenc + (size_t)tt * HD, nullptr, c0e);
        }
        gridbar(bar, NBLK * (++ph));
    }

    // ---- transition: hd = hf + hb; restage LDS for decoder roles ----
    {
        const float* hfF = heF + 0 * S;   // dir0, buf0 (final: 40 even)
        const float* hbF = heF + 2 * S;   // dir1, buf0
        for (int i = gid * 256 + tid; i < BB * HD; i += NBLK * 256) {
            const float v = hfF[i] + hbF[i];
            hdF[i] = v;
            hdB[i] = (__bf16)v;
        }
        if (gid < 56) {
            stage_w(wlds, WhhD, gid * 16);
        } else {
            const int b = gid - 56;
            const float4* src = (const float4*)(yenc + (size_t)b * TE * HD);
            float4* dst = (float4*)yencL;
            for (int i = tid; i < TE * HD / 4; i += 256) dst[i] = src[i];
        }
        gridbar(bar, NBLK * (++ph));
    }

    // ---- decoder: phase p runs GRU step p and (concurrently) attn step p-1 ----
    for (int p = 0; p <= TD; ++p) {
        if (p < TD && gid < 56) {
            const int cur = p & 1, nxt = cur ^ 1;
            gru_step(hdB + cur * S, hdF + cur * S, wlds,
                     GId + (size_t)p * BB * G3, bhhD,
                     hdF + nxt * S, hdB + nxt * S,
                     nullptr, Zb + (size_t)p * BB * KZ, gid * 16);
        }
        if (p >= 1 && gid >= 56) {
            attn_step(yencL, h2s, scL, attwL, hdF + (size_t)(p & 1) * S,
                      gid - 56, Zb + (size_t)(p - 1) * BB * KZ);
        }
        gridbar(bar, NBLK * (++ph));
    }
}

// ---------------------------------------------------------------------------
// bf16 MFMA GEMM, C = A @ B^T (+bias). M-major block order + bijective XCD
// swizzle (m204). MODE 0: C[M][N]. MODE 1: FC epilogue into d_out layout.
// ---------------------------------------------------------------------------
template<int BM, int BN, int WGM, int WGN, int MODE>
__global__ __launch_bounds__(256) void gemm_bt(
    const __bf16* __restrict__ A0, const __bf16* __restrict__ B0,
    float* __restrict__ C0, const float* __restrict__ bias0,
    const __bf16* __restrict__ A1, const __bf16* __restrict__ B1,
    float* __restrict__ C1, const float* __restrict__ bias1,
    int M, int N, int K, int Nreal)
{
    constexpr int BK = 32, PAD = 8;
    constexpr int WM = BM / WGM, WN = BN / WGN;
    constexpr int FM = WM / 16, FN = WN / 16;
    constexpr int LDS_W = BK + PAD;

    const __bf16* A = A0; const __bf16* Bp = B0;
    float* C = C0; const float* bias = bias0;
    if (blockIdx.z == 1) { A = A1; Bp = B1; C = C1; bias = bias1; }

    __shared__ __bf16 Ash[BM][LDS_W];
    __shared__ __bf16 Bsh[BN][LDS_W];

    const int tid  = threadIdx.x;
    const int lane = tid & 63;
    const int wave = tid >> 6;
    const int wr = wave / WGN, wc = wave % WGN;

    // bijective XCD swizzle + M-major tile order (consecutive ids share B-panel)
    const int nwg = gridDim.x * gridDim.y;
    const int orig = blockIdx.y * gridDim.x + blockIdx.x;
    const int q = nwg >> 3, r = nwg & 7;
    const int xcd = orig & 7, idx = orig >> 3;
    const int wg = (xcd < r ? xcd * (q + 1) : r * (q + 1) + (xcd - r) * q) + idx;
    const int mtiles = gridDim.y;
    const long tileM = (long)(wg % mtiles) * BM;
    const long tileN = (long)(wg / mtiles) * BN;

    const int r16 = lane & 15;
    const int hi  = lane >> 4;

    f32x4 acc[FM][FN];
    const f32x4 zero = {0.f, 0.f, 0.f, 0.f};
#pragma unroll
    for (int m = 0; m < FM; ++m)
#pragma unroll
        for (int n = 0; n < FN; ++n) acc[m][n] = zero;

    for (int k0 = 0; k0 < K; k0 += BK) {
#pragma unroll
        for (int it = 0; it < (BM * 4) / 256; ++it) {
            int id = it * 256 + tid;
            int rr = id >> 2, cv = (id & 3) << 3;
            *(u32x4*)&Ash[rr][cv] = *(const u32x4*)&A[(tileM + rr) * K + k0 + cv];
        }
#pragma unroll
        for (int it = 0; it < (BN * 4) / 256; ++it) {
            int id = it * 256 + tid;
            int rr = id >> 2, cv = (id & 3) << 3;
            *(u32x4*)&Bsh[rr][cv] = *(const u32x4*)&Bp[(tileN + rr) * K + k0 + cv];
        }
        __syncthreads();

        bf16x8 af[FM], bfr[FN];
#pragma unroll
        for (int m = 0; m < FM; ++m)
            af[m] = *(const bf16x8*)&Ash[wr * WM + m * 16 + r16][hi * 8];
#pragma unroll
        for (int n = 0; n < FN; ++n)
            bfr[n] = *(const bf16x8*)&Bsh[wc * WN + n * 16 + r16][hi * 8];
#pragma unroll
        for (int m = 0; m < FM; ++m)
#pragma unroll
            for (int n = 0; n < FN; ++n)
                acc[m][n] = __builtin_amdgcn_mfma_f32_16x16x32_bf16(af[m], bfr[n], acc[m][n], 0, 0, 0);
        __syncthreads();
    }

#pragma unroll
    for (int m = 0; m < FM; ++m) {
#pragma unroll
        for (int n = 0; n < FN; ++n) {
            const long gcol = tileN + wc * WN + n * 16 + r16;
            if (MODE == 1 && gcol >= Nreal) continue;
            const float bv = bias ? bias[gcol] : 0.0f;
#pragma unroll
            for (int rr = 0; rr < 4; ++rr) {
                const long grow = tileM + wr * WM + m * 16 + hi * 4 + rr;
                const float v = acc[m][n][rr] + bv;
                if (MODE == 0) {
                    C[grow * N + gcol] = v;
                } else {
                    const long t = grow >> 6, b = grow & 63;
                    C[(b * TD + t) * VO + gcol] = v;
                }
            }
        }
    }
}

// fp32 -> bf16 convert with row/col zero-padding
__global__ __launch_bounds__(256) void conv_pad(const float* __restrict__ src,
                                                __bf16* __restrict__ dst,
                                                int Rout, int Rin, int Kout, int Kin)
{
    size_t i = (size_t)blockIdx.x * 256 + threadIdx.x;
    const size_t total = (size_t)Rout * Kout;
    const size_t stride = (size_t)gridDim.x * 256;
    for (; i < total; i += stride) {
        int k = (int)(i % Kout);
        int r = (int)(i / Kout);
        float v = (r < Rin && k < Kin) ? src[(size_t)r * Kin + k] : 0.0f;
        dst[i] = (__bf16)v;
    }
}

// gather token embeddings into padded bf16 matrix X[(t*B+b)][EP]
__global__ __launch_bounds__(256) void gather_embed(const int* __restrict__ tok,
                                                    const float* __restrict__ emb,
                                                    __bf16* __restrict__ X)
{
    int i = blockIdx.x * 256 + threadIdx.x;
    const int total = TE * BB * EP;
    for (; i < total; i += gridDim.x * 256) {
        int e = i % EP;
        int row = i / EP;
        int t = row >> 6, b = row & 63;
        float v = 0.0f;
        if (e < ED) v = emb[(size_t)tok[b * TE + t] * ED + e];
        X[i] = (__bf16)v;
    }
}

// LDS-staged row softmax: 1 HBM read + 1 HBM write
__global__ __launch_bounds__(256) void softmax_kernel(float* __restrict__ out)
{
    __shared__ float row[VO];          // 120,000 B
    __shared__ float red[4];
    const size_t base = (size_t)blockIdx.x * VO;
    const int tid = threadIdx.x;

    float m = -1e30f;
    for (int ch = tid; ch < VO / 4; ch += 256) {
        const float4 x = *(const float4*)&out[base + ch * 4];
        *(float4*)&row[ch * 4] = x;
        m = fmaxf(fmaxf(fmaxf(m, x.x), x.y), fmaxf(x.z, x.w));
    }
    m = fmaxf(m, __shfl_down(m, 32)); m = fmaxf(m, __shfl_down(m, 16));
    m = fmaxf(m, __shfl_down(m, 8));  m = fmaxf(m, __shfl_down(m, 4));
    m = fmaxf(m, __shfl_down(m, 2));  m = fmaxf(m, __shfl_down(m, 1));
    if ((tid & 63) == 0) red[tid >> 6] = m;
    __syncthreads();
    m = fmaxf(fmaxf(red[0], red[1]), fmaxf(red[2], red[3]));

    float s = 0.0f;
    for (int v = tid; v < VO; v += 256) s += __expf(row[v] - m);
    s += __shfl_down(s, 32); s += __shfl_down(s, 16); s += __shfl_down(s, 8);
    s += __shfl_down(s, 4);  s += __shfl_down(s, 2);  s += __shfl_down(s, 1);
    __syncthreads();
    if ((tid & 63) == 0) red[tid >> 6] = s;
    __syncthreads();
    s = red[0] + red[1] + red[2] + red[3];

    const float inv = 1.0f / s;
    for (int ch = tid; ch < VO / 4; ch += 256) {
        float4 x = *(const float4*)&row[ch * 4];
        x.x = __expf(x.x - m) * inv;
        x.y = __expf(x.y - m) * inv;
        x.z = __expf(x.z - m) * inv;
        x.w = __expf(x.w - m) * inv;
        *(float4*)&out[base + ch * 4] = x;
    }
}

extern "C" void kernel_launch(void* const* d_in, const int* in_sizes, int n_in,
                              void* d_out, int out_size, void* d_ws, size_t ws_size,
                              hipStream_t stream)
{
    if (n_in < 18) return;
    const int*   x_enc   = (const int*)d_in[0];
    const int*   x_dec   = (const int*)d_in[1];
    const float* emb_enc = (const float*)d_in[2];
    const float* Wih_f   = (const float*)d_in[3];
    const float* Whh_f   = (const float*)d_in[4];
    const float* bih_f   = (const float*)d_in[5];
    const float* bhh_f   = (const float*)d_in[6];
    const float* Wih_b   = (const float*)d_in[7];
    const float* Whh_b   = (const float*)d_in[8];
    const float* bih_b   = (const float*)d_in[9];
    const float* bhh_b   = (const float*)d_in[10];
    const float* emb_dec = (const float*)d_in[11];
    const float* Wih_d   = (const float*)d_in[12];
    const float* Whh_d   = (const float*)d_in[13];
    const float* bih_d   = (const float*)d_in[14];
    const float* bhh_d   = (const float*)d_in[15];
    const float* fc_W    = (const float*)d_in[16];
    const float* fc_b    = (const float*)d_in[17];
    float* out = (float*)d_out;

    size_t off = 0;
    auto alloc = [&](size_t bytes) -> void* {
        void* p = (char*)d_ws + off;
        off = (off + bytes + 255) & ~(size_t)255;
        return p;
    };
    __bf16* fcWb  = (__bf16*)alloc((size_t)VP * KZ * 2);
    __bf16* WihFb = (__bf16*)alloc((size_t)G3 * EP * 2);
    __bf16* WihBb = (__bf16*)alloc((size_t)G3 * EP * 2);
    __bf16* WihDb = (__bf16*)alloc((size_t)G3 * EP * 2);
    __bf16* Xe    = (__bf16*)alloc((size_t)MR * EP * 2);
    __bf16* Xd    = (__bf16*)alloc((size_t)MR * EP * 2);
    float*  GIf   = (float*)alloc((size_t)MR * G3 * 4);
    float*  GIb   = (float*)alloc((size_t)MR * G3 * 4);
    float*  GId   = (float*)alloc((size_t)MR * G3 * 4);
    __bf16* Zb    = (__bf16*)alloc((size_t)MR * KZ * 2);
    char* zero_start = (char*)d_ws + off;
    float*  yenc  = (float*)alloc((size_t)BB * TE * HD * 4);
    float*  heF   = (float*)alloc((size_t)4 * BB * HD * 4);   // [dir][buf]
    __bf16* heB   = (__bf16*)alloc((size_t)4 * BB * HD * 2);
    int*    bar   = (int*)alloc(256);
    size_t zero_bytes = (size_t)(((char*)d_ws + off) - zero_start);
    float*  hdF   = (float*)alloc((size_t)2 * BB * HD * 4);
    __bf16* hdB   = (__bf16*)alloc((size_t)2 * BB * HD * 2);
    if (off > ws_size) return;   // ~220 MB required; fail visibly (zero output)

    // ---- init + weight conversion + embedding gather ----
    hipMemsetAsync(zero_start, 0, zero_bytes, stream);
    conv_pad<<<8192, 256, 0, stream>>>(fc_W,  fcWb,  VP, VO, KZ, KZ);
    conv_pad<<<3360, 256, 0, stream>>>(Wih_f, WihFb, G3, G3, EP, ED);
    conv_pad<<<3360, 256, 0, stream>>>(Wih_b, WihBb, G3, G3, EP, ED);
    conv_pad<<<3360, 256, 0, stream>>>(Wih_d, WihDb, G3, G3, EP, ED);
    gather_embed<<<3200, 256, 0, stream>>>(x_enc, emb_enc, Xe);
    gather_embed<<<3200, 256, 0, stream>>>(x_dec, emb_dec, Xd);

    // ---- batched input-side GEMMs: GI = X @ Wih^T + bih ----
    gemm_bt<128, 128, 2, 2, 0><<<dim3(G3 / 128, MR / 128, 2), 256, 0, stream>>>(
        Xe, WihFb, GIf, bih_f, Xe, WihBb, GIb, bih_b, MR, G3, EP, G3);
    gemm_bt<128, 128, 2, 2, 0><<<dim3(G3 / 128, MR / 128, 1), 256, 0, stream>>>(
        Xd, WihDb, GId, bih_d, nullptr, nullptr, nullptr, nullptr, MR, G3, EP, G3);

    // ---- persistent recurrence: encoder + decoder + attention ----
    recur<<<NBLK, 256, 0, stream>>>(GIf, GIb, GId, Whh_f, Whh_b, Whh_d,
                                    bhh_f, bhh_b, bhh_d,
                                    heF, heB, hdF, hdB, yenc, Zb, bar);

    // ---- batched FC: logits = Z @ fc_W^T + fc_b -> d_out ----
    gemm_bt<128, 128, 2, 2, 1><<<dim3(VP / 128, MR / 128, 1), 256, 0, stream>>>(
        Zb, fcWb, out, fc_b, nullptr, nullptr, nullptr, nullptr, MR, VP, KZ, VO);

    // ---- in-place row softmax ----
    softmax_kernel<<<BB * TD, 256, 0, stream>>>(out);
}

// Round 3
// 1741.753 us; speedup vs baseline: 2.2688x; 1.2994x over previous
//
#include <hip/hip_runtime.h>

// ---- problem constants ----
#define BB 64      // batch
#define TE 40      // encoder steps
#define TD 40      // decoder steps
#define ED 300     // embedding dim
#define EP 320     // padded embedding dim (mult of 32)
#define HD 896     // hidden
#define G3 2688    // 3*H
#define VO 30000   // vocab out
#define VP 30080   // padded vocab (235*128)
#define KZ 1792    // 2*H
#define MR 2560    // T*B rows
#define NBLK 120   // persistent-kernel grid (1 block/CU by LDS; all co-resident)

typedef __attribute__((ext_vector_type(8))) __bf16 bf16x8;
typedef __attribute__((ext_vector_type(4))) float f32x4;
typedef __attribute__((ext_vector_type(4))) unsigned int u32x4;

__device__ __forceinline__ float sig_(float x)  { return 1.0f / (1.0f + __expf(-x)); }
__device__ __forceinline__ float tanh_(float x) { return 1.0f - 2.0f / (__expf(2.0f * x) + 1.0f); }

// ---- coherent (cross-XCD) access helpers: sc0 sc1 = read/write the L3
// coherence point, leaving L2 intact (no buffer_wbl2 / buffer_inv needed). ----
__device__ __forceinline__ bf16x8 ld128_sc(const __bf16* p) {
    bf16x8 r;
    asm volatile("global_load_dwordx4 %0, %1, off sc0 sc1" : "=v"(r) : "v"(p));
    return r;   // NOT ready until vm_wait0()
}
__device__ __forceinline__ float ldf_sc(const float* p) {
    float r;
    asm volatile("global_load_dword %0, %1, off sc0 sc1" : "=v"(r) : "v"(p));
    return r;   // NOT ready until vm_wait0()
}
__device__ __forceinline__ void vm_wait0() {
    asm volatile("s_waitcnt vmcnt(0)" ::: "memory");
}
__device__ __forceinline__ void stf_sc(float* p, float v) {
    asm volatile("global_store_dword %0, %1, off sc0 sc1" :: "v"(p), "v"(v) : "memory");
}
__device__ __forceinline__ void sth_sc(__bf16* p, float v) {
    unsigned int u = (unsigned int)__builtin_bit_cast(unsigned short, (__bf16)v);
    asm volatile("global_store_short %0, %1, off sc0 sc1" :: "v"(p), "v"(u) : "memory");
}

// ---------------------------------------------------------------------------
// Grid barrier. Steady-state (full=false): RELAXED arrive + RELAXED spin —
// no L2 writeback, no L2 invalidate. Ordering: each wave drains vmcnt(0)
// (sc1 stores committed at L3) before s_barrier; thread0's sc1 atomic is
// issued after. Transition (full=true): RELEASE arrive (buffer_wbl2 flushes
// normal dirty lines, e.g. yenc) + ACQUIRE fence after spin (buffer_inv).
// ---------------------------------------------------------------------------
__device__ __forceinline__ void gridbar(int* cnt, int target, bool full)
{
    vm_wait0();
    __syncthreads();
    if (threadIdx.x == 0) {
        if (full) __hip_atomic_fetch_add(cnt, 1, __ATOMIC_RELEASE, __HIP_MEMORY_SCOPE_AGENT);
        else      __hip_atomic_fetch_add(cnt, 1, __ATOMIC_RELAXED, __HIP_MEMORY_SCOPE_AGENT);
        while (__hip_atomic_load(cnt, __ATOMIC_RELAXED, __HIP_MEMORY_SCOPE_AGENT) < target)
            __builtin_amdgcn_s_sleep(4);
        if (full) __builtin_amdgcn_fence(__ATOMIC_ACQUIRE, "agent");
    }
    __syncthreads();
    asm volatile("" ::: "memory");
}

// ---------------------------------------------------------------------------
// Stage 48 Whh rows (3 gates x 16 cols) fp32 -> bf16 LDS in FRAGMENT order:
// wlds[((g*28 + kk)*64 + lane)*8 + j] = Whh[g*HD + c0 + (lane&15)][kk*32 + (lane>>4)*8 + j]
// -> ds_read_b128 at consecutive 16B per lane = conflict-free.
// ---------------------------------------------------------------------------
__device__ __forceinline__ void stage_w(__bf16* wlds, const float* __restrict__ W, int c0)
{
    const int tid = threadIdx.x;
    for (int ch = tid; ch < 48 * 224; ch += 256) {
        const int lr = ch / 224, c4 = (ch % 224) * 4;
        const int g = lr >> 4, rr = lr & 15;
        const int kk = c4 >> 5, hi = (c4 & 31) >> 3, j = c4 & 7;   // j in {0,4}
        const float4 v = *(const float4*)&W[(size_t)(g * HD + c0 + rr) * HD + c4];
        __bf16* d = &wlds[((g * 28 + kk) * 64 + hi * 16 + rr) * 8 + j];
        d[0] = (__bf16)v.x; d[1] = (__bf16)v.y; d[2] = (__bf16)v.z; d[3] = (__bf16)v.w;
    }
}

struct GiReg { float g0[4], g1[4], g2[4]; };

// prefetch x-side gate pre-activations for one step (normal loads; issued
// before the barrier, consumed after — latency hidden under the barrier wait)
__device__ __forceinline__ GiReg gi_prefetch(const float* __restrict__ GIt,
                                             int c, int w, int hi)
{
    GiReg r;
#pragma unroll
    for (int rg = 0; rg < 4; ++rg) {
        const float* gp = GIt + (size_t)(16 * w + hi * 4 + rg) * G3 + c;
        r.g0[rg] = gp[0]; r.g1[rg] = gp[HD]; r.g2[rg] = gp[2 * HD];
    }
    return r;
}

// ---------------------------------------------------------------------------
// One GRU step for this block's 16 c-values, all 64 batch rows.
// wave w = batch rows 16w..16w+15; 3 MFMA chains = the 3 gates.
// h traffic is sc1 (cross-XCD coherent); GI comes prefetched in registers.
// ---------------------------------------------------------------------------
__device__ __forceinline__ void gru_step(
    const __bf16* __restrict__ hcurB, const float* __restrict__ hcurF,
    const __bf16* __restrict__ wlds, const GiReg& gi,
    float bh0, float bh1, float bh2,
    float* __restrict__ hnF, __bf16* __restrict__ hnB,
    float* __restrict__ yencD_tt,     // yenc_dir + tt*HD ([b][t][c] layout) or null
    __bf16* __restrict__ zrow,        // Zb + s*BB*KZ or null
    int c0, int lane, int w)
{
    const int r16 = lane & 15, hi = lane >> 4;
    const int c = c0 + r16;
    const int brow = 16 * w;

    // batched independent sc1 loads: 28 A-fragments + 4 h_prev scalars
    bf16x8 afr[28];
    const __bf16* ap = hcurB + (size_t)(brow + r16) * HD + hi * 8;
#pragma unroll
    for (int kk = 0; kk < 28; ++kk) afr[kk] = ld128_sc(ap + kk * 32);
    const float* hpp = hcurF + (size_t)(brow + hi * 4) * HD + c;
    const float hp0 = ldf_sc(hpp);
    const float hp1 = ldf_sc(hpp + HD);
    const float hp2 = ldf_sc(hpp + 2 * HD);
    const float hp3 = ldf_sc(hpp + 3 * HD);
    vm_wait0();
    __builtin_amdgcn_sched_barrier(0);

    f32x4 a0 = {0.f, 0.f, 0.f, 0.f}, a1 = a0, a2 = a0;
#pragma unroll
    for (int kk = 0; kk < 28; ++kk) {
        const bf16x8 b0 = *(const bf16x8*)&wlds[(kk) * 512 + lane * 8];
        const bf16x8 b1 = *(const bf16x8*)&wlds[(28 + kk) * 512 + lane * 8];
        const bf16x8 b2 = *(const bf16x8*)&wlds[(56 + kk) * 512 + lane * 8];
        a0 = __builtin_amdgcn_mfma_f32_16x16x32_bf16(afr[kk], b0, a0, 0, 0, 0);
        a1 = __builtin_amdgcn_mfma_f32_16x16x32_bf16(afr[kk], b1, a1, 0, 0, 0);
        a2 = __builtin_amdgcn_mfma_f32_16x16x32_bf16(afr[kk], b2, a2, 0, 0, 0);
    }

    const float hpv[4] = {hp0, hp1, hp2, hp3};
#pragma unroll
    for (int rg = 0; rg < 4; ++rg) {
        const int b = brow + hi * 4 + rg;
        const float rr = sig_(gi.g0[rg] + a0[rg] + bh0);
        const float zz = sig_(gi.g1[rg] + a1[rg] + bh1);
        const float nn = tanh_(gi.g2[rg] + rr * (a2[rg] + bh2));
        const float hnew = (1.0f - zz) * nn + zz * hpv[rg];
        stf_sc(hnF + (size_t)b * HD + c, hnew);
        sth_sc(hnB + (size_t)b * HD + c, hnew);
        if (yencD_tt) yencD_tt[(size_t)b * TE * HD + c] = hnew;   // normal store
        if (zrow)    zrow[(size_t)b * KZ + c] = (__bf16)hnew;     // normal store
    }
}

// attention for one batch element b (yenc[b] summed & resident in LDS)
__device__ __forceinline__ void attn_step(
    const float* __restrict__ yencL, float* __restrict__ h2s,
    float* __restrict__ scL, float* __restrict__ attwL,
    const float* __restrict__ h2g, int b, __bf16* __restrict__ zr)
{
    const int tid = threadIdx.x, lane = tid & 63, w = tid >> 6;

    // stage h2 (sc1 -> LDS), batched then one wait
    const float* hb_ = h2g + (size_t)b * HD;
    const float a0 = ldf_sc(hb_ + tid);
    const float a1 = ldf_sc(hb_ + tid + 256);
    const float a2 = ldf_sc(hb_ + tid + 512);
    const float a3 = (tid < HD - 768) ? ldf_sc(hb_ + tid + 768) : 0.0f;
    vm_wait0();
    h2s[tid] = a0; h2s[tid + 256] = a1; h2s[tid + 512] = a2;
    if (tid < HD - 768) h2s[tid + 768] = a3;
    __syncthreads();

    const float2* h22 = (const float2*)h2s;
    for (int t = w; t < TE; t += 4) {
        const float2* y2 = (const float2*)(yencL + t * HD);
        float p = 0.f;
#pragma unroll
        for (int it = 0; it < HD / 128; ++it) {
            const float2 ya = y2[lane + it * 64];
            const float2 hb2 = h22[lane + it * 64];
            p += ya.x * hb2.x + ya.y * hb2.y;
        }
        p += __shfl_down(p, 32); p += __shfl_down(p, 16); p += __shfl_down(p, 8);
        p += __shfl_down(p, 4);  p += __shfl_down(p, 2);  p += __shfl_down(p, 1);
        if (lane == 0) scL[t] = p;
    }
    __syncthreads();

    float m = scL[0];
    for (int t = 1; t < TE; ++t) m = fmaxf(m, scL[t]);
    float s = 0.f;
    for (int t = 0; t < TE; ++t) s += __expf(scL[t] - m);
    const float inv = 1.0f / s;
    if (tid < TE) attwL[tid] = __expf(scL[tid] - m) * inv;
    __syncthreads();

    for (int c = tid; c < HD; c += 256) {
        float acc = 0.f;
#pragma unroll
        for (int t = 0; t < TE; ++t) acc += attwL[t] * yencL[t * HD + c];
        zr[(size_t)b * KZ + HD + c] = (__bf16)acc;   // normal store (read post-kernel)
    }
}

// ---------------------------------------------------------------------------
// Persistent recurrence kernel.
// Encoder: blocks 0..55 fwd GRU, 56..111 bwd GRU (16 cols each), 112..119 idle.
// Decoder: blocks 0..55 GRU; blocks 56..119 attention (b = gid-56), with
// attn step p-1 overlapping GRU step p.
// ---------------------------------------------------------------------------
__global__ __launch_bounds__(256, 1) void recur(
    const float* __restrict__ GIf, const float* __restrict__ GIb,
    const float* __restrict__ GId,
    const float* __restrict__ WhhF, const float* __restrict__ WhhB,
    const float* __restrict__ WhhD,
    const float* __restrict__ bhhF, const float* __restrict__ bhhB,
    const float* __restrict__ bhhD,
    float* __restrict__ heF, __bf16* __restrict__ heB,   // [dir][buf][BB*HD]
    float* __restrict__ hdF, __bf16* __restrict__ hdB,   // [buf][BB*HD]
    float* __restrict__ yenc_f, float* __restrict__ yenc_b,  // [b][t][c]
    __bf16* __restrict__ Zb, int* __restrict__ bar)
{
    __shared__ __align__(16) char smem[147456];
    __bf16* wlds  = (__bf16*)smem;                 // gru role: 3*28*64*8 bf16 (86,016 B)
    float*  yencL = (float*)smem;                  // attn role: [40][896] f32 (143,360 B)
    float*  h2s   = (float*)(smem + 143360);       // [896]
    float*  scL   = (float*)(smem + 146944);       // [40]
    float*  attwL = (float*)(smem + 147136);       // [40]

    const int gid = blockIdx.x;
    const int tid = threadIdx.x;
    const int lane = tid & 63, w = tid >> 6;
    const int r16 = lane & 15, hi = lane >> 4;
    const size_t S = (size_t)BB * HD;
    int ph = 0;

    // ---- encoder setup ----
    const bool eGru = gid < 112;
    const int dir = (gid >= 56) ? 1 : 0;
    const int c0e = (eGru ? (dir ? gid - 56 : gid) : 0) * 16;
    const float* GIe  = dir ? GIb : GIf;
    const float* bhhE = dir ? bhhB : bhhF;
    float* yencD = dir ? yenc_b : yenc_f;
    float eb0 = 0.f, eb1 = 0.f, eb2 = 0.f;
    GiReg gi;
    if (eGru) {
        stage_w(wlds, dir ? WhhB : WhhF, c0e);
        const int ce = c0e + r16;
        eb0 = bhhE[ce]; eb1 = bhhE[HD + ce]; eb2 = bhhE[2 * HD + ce];
        gi = gi_prefetch(GIe + (size_t)(dir ? TE - 1 : 0) * BB * G3, ce, w, hi);
    }
    __syncthreads();

    // ---- encoder: 40 phases ----
    for (int t = 0; t < TE; ++t) {
        if (eGru) {
            const int tt = dir ? (TE - 1 - t) : t;
            const int cur = t & 1, nxt = cur ^ 1;
            gru_step(heB + (dir * 2 + cur) * S, heF + (dir * 2 + cur) * S, wlds, gi,
                     eb0, eb1, eb2,
                     heF + (dir * 2 + nxt) * S, heB + (dir * 2 + nxt) * S,
                     yencD + (size_t)tt * HD, nullptr, c0e, lane, w);
            if (t + 1 < TE) {
                const int ttn = dir ? (TE - 2 - t) : (t + 1);
                gi = gi_prefetch(GIe + (size_t)ttn * BB * G3, c0e + r16, w, hi);
            }
        }
        gridbar(bar, NBLK * (++ph), false);
    }

    // ---- transition: hd = hf + hb (sc1); restage LDS; prefetch GId[0] ----
    {
        const int i0 = gid * 256 + tid;
        const int i1 = i0 + NBLK * 256;
        const bool has1 = (i1 < BB * HD);
        const float f0 = ldf_sc(&heF[0 * S + i0]);
        const float b0 = ldf_sc(&heF[2 * S + i0]);
        const float f1 = has1 ? ldf_sc(&heF[0 * S + i1]) : 0.f;
        const float b1 = has1 ? ldf_sc(&heF[2 * S + i1]) : 0.f;
        vm_wait0();
        const float v0 = f0 + b0;
        stf_sc(&hdF[i0], v0); sth_sc(&hdB[i0], v0);
        if (has1) { const float v1 = f1 + b1; stf_sc(&hdF[i1], v1); sth_sc(&hdB[i1], v1); }

        float db0 = 0.f, db1 = 0.f, db2 = 0.f;
        if (gid < 56) {
            stage_w(wlds, WhhD, gid * 16);
            const int cd = gid * 16 + r16;
            db0 = bhhD[cd]; db1 = bhhD[HD + cd]; db2 = bhhD[2 * HD + cd];
            gi = gi_prefetch(GId, cd, w, hi);
        }
        eb0 = db0; eb1 = db1; eb2 = db2;     // reuse registers for decoder bias
        if (gid < 56) { eb0 = db0; eb1 = db1; eb2 = db2; }
        gridbar(bar, NBLK * (++ph), true);   // full: flush yenc, inv stale lines

        // ---- decoder: 41 phases ----
        for (int p = 0; p <= TD; ++p) {
            if (gid < 56) {
                if (p < TD) {
                    const int cur = p & 1, nxt = cur ^ 1;
                    gru_step(hdB + cur * S, hdF + cur * S, wlds, gi,
                             eb0, eb1, eb2,
                             hdF + nxt * S, hdB + nxt * S,
                             nullptr, Zb + (size_t)p * BB * KZ, gid * 16, lane, w);
                    if (p + 1 < TD)
                        gi = gi_prefetch(GId + (size_t)(p + 1) * BB * G3, gid * 16 + r16, w, hi);
                }
            } else {
                const int b = gid - 56;
                if (p == 0) {
                    // stage yencL = yenc_f[b] + yenc_b[b] (post-inv, safe)
                    const float4* sf = (const float4*)(yenc_f + (size_t)b * TE * HD);
                    const float4* sb = (const float4*)(yenc_b + (size_t)b * TE * HD);
                    float4* dst = (float4*)yencL;
                    for (int i = tid; i < TE * HD / 4; i += 256) {
                        float4 xa = sf[i]; const float4 xb = sb[i];
                        xa.x += xb.x; xa.y += xb.y; xa.z += xb.z; xa.w += xb.w;
                        dst[i] = xa;
                    }
                } else {
                    attn_step(yencL, h2s, scL, attwL, hdF + (size_t)(p & 1) * S,
                              b, Zb + (size_t)(p - 1) * BB * KZ);
                }
            }
            if (p < TD) gridbar(bar, NBLK * (++ph), false);
        }
    }
}

// ---------------------------------------------------------------------------
// bf16 MFMA GEMM, C = A @ B^T (+bias), M-major order + bijective XCD swizzle.
// MODE 0: C[M][N]. MODE 1: FC epilogue into d_out layout.
// ---------------------------------------------------------------------------
template<int BM, int BN, int WGM, int WGN, int MODE>
__global__ __launch_bounds__(256) void gemm_bt(
    const __bf16* __restrict__ A0, const __bf16* __restrict__ B0,
    float* __restrict__ C0, const float* __restrict__ bias0,
    const __bf16* __restrict__ A1, const __bf16* __restrict__ B1,
    float* __restrict__ C1, const float* __restrict__ bias1,
    int M, int N, int K, int Nreal)
{
    constexpr int BK = 32, PAD = 8;
    constexpr int WM = BM / WGM, WN = BN / WGN;
    constexpr int FM = WM / 16, FN = WN / 16;
    constexpr int LDS_W = BK + PAD;

    const __bf16* A = A0; const __bf16* Bp = B0;
    float* C = C0; const float* bias = bias0;
    if (blockIdx.z == 1) { A = A1; Bp = B1; C = C1; bias = bias1; }

    __shared__ __bf16 Ash[BM][LDS_W];
    __shared__ __bf16 Bsh[BN][LDS_W];

    const int tid  = threadIdx.x;
    const int lane = tid & 63;
    const int wave = tid >> 6;
    const int wr = wave / WGN, wc = wave % WGN;

    const int nwg = gridDim.x * gridDim.y;
    const int orig = blockIdx.y * gridDim.x + blockIdx.x;
    const int q = nwg >> 3, r = nwg & 7;
    const int xcd = orig & 7, idx = orig >> 3;
    const int wg = (xcd < r ? xcd * (q + 1) : r * (q + 1) + (xcd - r) * q) + idx;
    const int mtiles = gridDim.y;
    const long tileM = (long)(wg % mtiles) * BM;
    const long tileN = (long)(wg / mtiles) * BN;

    const int r16 = lane & 15;
    const int hi  = lane >> 4;

    f32x4 acc[FM][FN];
    const f32x4 zero = {0.f, 0.f, 0.f, 0.f};
#pragma unroll
    for (int m = 0; m < FM; ++m)
#pragma unroll
        for (int n = 0; n < FN; ++n) acc[m][n] = zero;

    for (int k0 = 0; k0 < K; k0 += BK) {
#pragma unroll
        for (int it = 0; it < (BM * 4) / 256; ++it) {
            int id = it * 256 + tid;
            int rr = id >> 2, cv = (id & 3) << 3;
            *(u32x4*)&Ash[rr][cv] = *(const u32x4*)&A[(tileM + rr) * K + k0 + cv];
        }
#pragma unroll
        for (int it = 0; it < (BN * 4) / 256; ++it) {
            int id = it * 256 + tid;
            int rr = id >> 2, cv = (id & 3) << 3;
            *(u32x4*)&Bsh[rr][cv] = *(const u32x4*)&Bp[(tileN + rr) * K + k0 + cv];
        }
        __syncthreads();

        bf16x8 af[FM], bfr[FN];
#pragma unroll
        for (int m = 0; m < FM; ++m)
            af[m] = *(const bf16x8*)&Ash[wr * WM + m * 16 + r16][hi * 8];
#pragma unroll
        for (int n = 0; n < FN; ++n)
            bfr[n] = *(const bf16x8*)&Bsh[wc * WN + n * 16 + r16][hi * 8];
#pragma unroll
        for (int m = 0; m < FM; ++m)
#pragma unroll
            for (int n = 0; n < FN; ++n)
                acc[m][n] = __builtin_amdgcn_mfma_f32_16x16x32_bf16(af[m], bfr[n], acc[m][n], 0, 0, 0);
        __syncthreads();
    }

#pragma unroll
    for (int m = 0; m < FM; ++m) {
#pragma unroll
        for (int n = 0; n < FN; ++n) {
            const long gcol = tileN + wc * WN + n * 16 + r16;
            if (MODE == 1 && gcol >= Nreal) continue;
            const float bv = bias ? bias[gcol] : 0.0f;
#pragma unroll
            for (int rr = 0; rr < 4; ++rr) {
                const long grow = tileM + wr * WM + m * 16 + hi * 4 + rr;
                const float v = acc[m][n][rr] + bv;
                if (MODE == 0) {
                    C[grow * N + gcol] = v;
                } else {
                    const long t = grow >> 6, b = grow & 63;
                    C[(b * TD + t) * VO + gcol] = v;
                }
            }
        }
    }
}

// fp32 -> bf16 convert with row/col zero-padding
__global__ __launch_bounds__(256) void conv_pad(const float* __restrict__ src,
                                                __bf16* __restrict__ dst,
                                                int Rout, int Rin, int Kout, int Kin)
{
    size_t i = (size_t)blockIdx.x * 256 + threadIdx.x;
    const size_t total = (size_t)Rout * Kout;
    const size_t stride = (size_t)gridDim.x * 256;
    for (; i < total; i += stride) {
        int k = (int)(i % Kout);
        int r = (int)(i / Kout);
        float v = (r < Rin && k < Kin) ? src[(size_t)r * Kin + k] : 0.0f;
        dst[i] = (__bf16)v;
    }
}

// gather token embeddings into padded bf16 matrix X[(t*B+b)][EP]
__global__ __launch_bounds__(256) void gather_embed(const int* __restrict__ tok,
                                                    const float* __restrict__ emb,
                                                    __bf16* __restrict__ X)
{
    int i = blockIdx.x * 256 + threadIdx.x;
    const int total = TE * BB * EP;
    for (; i < total; i += gridDim.x * 256) {
        int e = i % EP;
        int row = i / EP;
        int t = row >> 6, b = row & 63;
        float v = 0.0f;
        if (e < ED) v = emb[(size_t)tok[b * TE + t] * ED + e];
        X[i] = (__bf16)v;
    }
}

// LDS-staged row softmax: 1 HBM read + 1 HBM write
__global__ __launch_bounds__(256) void softmax_kernel(float* __restrict__ out)
{
    __shared__ float row[VO];
    __shared__ float red[4];
    const size_t base = (size_t)blockIdx.x * VO;
    const int tid = threadIdx.x;

    float m = -1e30f;
    for (int ch = tid; ch < VO / 4; ch += 256) {
        const float4 x = *(const float4*)&out[base + ch * 4];
        *(float4*)&row[ch * 4] = x;
        m = fmaxf(fmaxf(fmaxf(m, x.x), x.y), fmaxf(x.z, x.w));
    }
    m = fmaxf(m, __shfl_down(m, 32)); m = fmaxf(m, __shfl_down(m, 16));
    m = fmaxf(m, __shfl_down(m, 8));  m = fmaxf(m, __shfl_down(m, 4));
    m = fmaxf(m, __shfl_down(m, 2));  m = fmaxf(m, __shfl_down(m, 1));
    if ((tid & 63) == 0) red[tid >> 6] = m;
    __syncthreads();
    m = fmaxf(fmaxf(red[0], red[1]), fmaxf(red[2], red[3]));

    float s = 0.0f;
    for (int v = tid; v < VO; v += 256) s += __expf(row[v] - m);
    s += __shfl_down(s, 32); s += __shfl_down(s, 16); s += __shfl_down(s, 8);
    s += __shfl_down(s, 4);  s += __shfl_down(s, 2);  s += __shfl_down(s, 1);
    __syncthreads();
    if ((tid & 63) == 0) red[tid >> 6] = s;
    __syncthreads();
    s = red[0] + red[1] + red[2] + red[3];

    const float inv = 1.0f / s;
    for (int ch = tid; ch < VO / 4; ch += 256) {
        float4 x = *(const float4*)&row[ch * 4];
        x.x = __expf(x.x - m) * inv;
        x.y = __expf(x.y - m) * inv;
        x.z = __expf(x.z - m) * inv;
        x.w = __expf(x.w - m) * inv;
        *(float4*)&out[base + ch * 4] = x;
    }
}

extern "C" void kernel_launch(void* const* d_in, const int* in_sizes, int n_in,
                              void* d_out, int out_size, void* d_ws, size_t ws_size,
                              hipStream_t stream)
{
    if (n_in < 18) return;
    const int*   x_enc   = (const int*)d_in[0];
    const int*   x_dec   = (const int*)d_in[1];
    const float* emb_enc = (const float*)d_in[2];
    const float* Wih_f   = (const float*)d_in[3];
    const float* Whh_f   = (const float*)d_in[4];
    const float* bih_f   = (const float*)d_in[5];
    const float* bhh_f   = (const float*)d_in[6];
    const float* Wih_b   = (const float*)d_in[7];
    const float* Whh_b   = (const float*)d_in[8];
    const float* bih_b   = (const float*)d_in[9];
    const float* bhh_b   = (const float*)d_in[10];
    const float* emb_dec = (const float*)d_in[11];
    const float* Wih_d   = (const float*)d_in[12];
    const float* Whh_d   = (const float*)d_in[13];
    const float* bih_d   = (const float*)d_in[14];
    const float* bhh_d   = (const float*)d_in[15];
    const float* fc_W    = (const float*)d_in[16];
    const float* fc_b    = (const float*)d_in[17];
    float* out = (float*)d_out;

    size_t off = 0;
    auto alloc = [&](size_t bytes) -> void* {
        void* p = (char*)d_ws + off;
        off = (off + bytes + 255) & ~(size_t)255;
        return p;
    };
    __bf16* fcWb   = (__bf16*)alloc((size_t)VP * KZ * 2);
    __bf16* WihFb  = (__bf16*)alloc((size_t)G3 * EP * 2);
    __bf16* WihBb  = (__bf16*)alloc((size_t)G3 * EP * 2);
    __bf16* WihDb  = (__bf16*)alloc((size_t)G3 * EP * 2);
    __bf16* Xe     = (__bf16*)alloc((size_t)MR * EP * 2);
    __bf16* Xd     = (__bf16*)alloc((size_t)MR * EP * 2);
    float*  GIf    = (float*)alloc((size_t)MR * G3 * 4);
    float*  GIb    = (float*)alloc((size_t)MR * G3 * 4);
    float*  GId    = (float*)alloc((size_t)MR * G3 * 4);
    __bf16* Zb     = (__bf16*)alloc((size_t)MR * KZ * 2);
    float*  yenc_f = (float*)alloc((size_t)BB * TE * HD * 4);
    float*  yenc_b = (float*)alloc((size_t)BB * TE * HD * 4);
    float*  hdF    = (float*)alloc((size_t)2 * BB * HD * 4);
    __bf16* hdB    = (__bf16*)alloc((size_t)2 * BB * HD * 2);
    char* zero_start = (char*)d_ws + off;
    float*  heF    = (float*)alloc((size_t)4 * BB * HD * 4);   // [dir][buf]
    __bf16* heB    = (__bf16*)alloc((size_t)4 * BB * HD * 2);
    int*    bar    = (int*)alloc(256);
    size_t zero_bytes = (size_t)(((char*)d_ws + off) - zero_start);
    if (off > ws_size) return;   // ~230 MB required; fail visibly (zero output)

    // ---- init + weight conversion + embedding gather ----
    hipMemsetAsync(zero_start, 0, zero_bytes, stream);
    conv_pad<<<8192, 256, 0, stream>>>(fc_W,  fcWb,  VP, VO, KZ, KZ);
    conv_pad<<<3360, 256, 0, stream>>>(Wih_f, WihFb, G3, G3, EP, ED);
    conv_pad<<<3360, 256, 0, stream>>>(Wih_b, WihBb, G3, G3, EP, ED);
    conv_pad<<<3360, 256, 0, stream>>>(Wih_d, WihDb, G3, G3, EP, ED);
    gather_embed<<<3200, 256, 0, stream>>>(x_enc, emb_enc, Xe);
    gather_embed<<<3200, 256, 0, stream>>>(x_dec, emb_dec, Xd);

    // ---- batched input-side GEMMs: GI = X @ Wih^T + bih ----
    gemm_bt<128, 128, 2, 2, 0><<<dim3(G3 / 128, MR / 128, 2), 256, 0, stream>>>(
        Xe, WihFb, GIf, bih_f, Xe, WihBb, GIb, bih_b, MR, G3, EP, G3);
    gemm_bt<128, 128, 2, 2, 0><<<dim3(G3 / 128, MR / 128, 1), 256, 0, stream>>>(
        Xd, WihDb, GId, bih_d, nullptr, nullptr, nullptr, nullptr, MR, G3, EP, G3);

    // ---- persistent recurrence: encoder + decoder + attention ----
    recur<<<NBLK, 256, 0, stream>>>(GIf, GIb, GId, Whh_f, Whh_b, Whh_d,
                                    bhh_f, bhh_b, bhh_d,
                                    heF, heB, hdF, hdB, yenc_f, yenc_b, Zb, bar);

    // ---- batched FC: logits = Z @ fc_W^T + fc_b -> d_out ----
    gemm_bt<128, 128, 2, 2, 1><<<dim3(VP / 128, MR / 128, 1), 256, 0, stream>>>(
        Zb, fcWb, out, fc_b, nullptr, nullptr, nullptr, nullptr, MR, VP, KZ, VO);

    // ---- in-place row softmax ----
    softmax_kernel<<<BB * TD, 256, 0, stream>>>(out);
}

// Round 4
// 1660.072 us; speedup vs baseline: 2.3805x; 1.0492x over previous
//
#include <hip/hip_runtime.h>

// ---- problem constants ----
#define BB 64      // batch
#define TE 40      // encoder steps
#define TD 40      // decoder steps
#define ED 300     // embedding dim
#define EP 320     // padded embedding dim (mult of 32)
#define HD 896     // hidden
#define G3 2688    // 3*H
#define VO 30000   // vocab out
#define VP 30080   // padded vocab (235*128)
#define KZ 1792    // 2*H
#define MR 2560    // T*B rows
#define NBLK 120   // persistent-kernel grid (1 block/CU by LDS; all co-resident)

// flag regions (ints within the flags array)
#define FOFF 0     // encoder fwd, 56
#define BOFF 56    // encoder bwd, 56
#define DOFF 112   // decoder GRU, 56
#define AOFF 168   // decoder attn, 64
#define TOFF 232   // transition, 120

typedef __attribute__((ext_vector_type(8))) __bf16 bf16x8;
typedef __attribute__((ext_vector_type(4))) float f32x4;
typedef __attribute__((ext_vector_type(4))) unsigned int u32x4;

__device__ __forceinline__ float sig_(float x)  { return 1.0f / (1.0f + __expf(-x)); }
__device__ __forceinline__ float tanh_(float x) { return 1.0f - 2.0f / (__expf(2.0f * x) + 1.0f); }

// ---- coherent (cross-XCD) access helpers: sc0 sc1 = read/write the L3
// coherence point, bypassing L2 (no buffer_wbl2 / buffer_inv anywhere). ----
__device__ __forceinline__ bf16x8 ld128_sc(const __bf16* p) {
    bf16x8 r;
    asm volatile("global_load_dwordx4 %0, %1, off sc0 sc1" : "=v"(r) : "v"(p));
    return r;   // NOT ready until vm_wait0()
}
__device__ __forceinline__ f32x4 ldf4_sc(const float* p) {
    f32x4 r;
    asm volatile("global_load_dwordx4 %0, %1, off sc0 sc1" : "=v"(r) : "v"(p));
    return r;   // NOT ready until vm_wait0()
}
__device__ __forceinline__ float ldf_sc(const float* p) {
    float r;
    asm volatile("global_load_dword %0, %1, off sc0 sc1" : "=v"(r) : "v"(p));
    return r;   // NOT ready until vm_wait0()
}
__device__ __forceinline__ void vm_wait0() {
    asm volatile("s_waitcnt vmcnt(0)" ::: "memory");
}
__device__ __forceinline__ void stf_sc(float* p, float v) {
    asm volatile("global_store_dword %0, %1, off sc0 sc1" :: "v"(p), "v"(v) : "memory");
}
__device__ __forceinline__ void sth_sc(__bf16* p, float v) {
    unsigned int u = (unsigned int)__builtin_bit_cast(unsigned short, (__bf16)v);
    asm volatile("global_store_short %0, %1, off sc0 sc1" :: "v"(p), "v"(u) : "memory");
}
__device__ __forceinline__ void sti_sc(int* p, int v) {
    asm volatile("global_store_dword %0, %1, off sc0 sc1" :: "v"(p), "v"(v) : "memory");
}
// spin until *p >= target (sc1 load + wait fused in one asm block)
__device__ __forceinline__ void spin_ge(const int* p, int target) {
    int v;
    for (;;) {
        asm volatile("global_load_dword %0, %1, off sc0 sc1\n\ts_waitcnt vmcnt(0)"
                     : "=v"(v) : "v"(p) : "memory");
        if (v >= target) break;
        __builtin_amdgcn_s_sleep(1);
    }
}

// ---------------------------------------------------------------------------
// Stage 48 Whh rows (3 gates x 16 cols) fp32 -> bf16 LDS in FRAGMENT order:
// wlds[((g*28 + kk)*64 + hi*16 + r)*8 + j] -> ds_read_b128 conflict-free.
// ---------------------------------------------------------------------------
__device__ __forceinline__ void stage_w(__bf16* wlds, const float* __restrict__ W, int c0)
{
    const int tid = threadIdx.x;
    for (int ch = tid; ch < 48 * 224; ch += 256) {
        const int lr = ch / 224, c4 = (ch % 224) * 4;
        const int g = lr >> 4, rr = lr & 15;
        const int kk = c4 >> 5, hi = (c4 & 31) >> 3, j = c4 & 7;   // j in {0,4}
        const float4 v = *(const float4*)&W[(size_t)(g * HD + c0 + rr) * HD + c4];
        __bf16* d = &wlds[((g * 28 + kk) * 64 + hi * 16 + rr) * 8 + j];
        d[0] = (__bf16)v.x; d[1] = (__bf16)v.y; d[2] = (__bf16)v.z; d[3] = (__bf16)v.w;
    }
}

struct GiReg { float g0[4], g1[4], g2[4]; };

// prefetch x-side gate pre-activations for one step (normal loads, L2-cached)
__device__ __forceinline__ GiReg gi_prefetch(const float* __restrict__ GIt,
                                             int c, int w, int hi)
{
    GiReg r;
#pragma unroll
    for (int rg = 0; rg < 4; ++rg) {
        const float* gp = GIt + (size_t)(16 * w + hi * 4 + rg) * G3 + c;
        r.g0[rg] = gp[0]; r.g1[rg] = gp[HD]; r.g2[rg] = gp[2 * HD];
    }
    return r;
}

// ---------------------------------------------------------------------------
// One GRU step for this block's 16 c-values, all 64 batch rows.
// ---------------------------------------------------------------------------
__device__ __forceinline__ void gru_step(
    const __bf16* __restrict__ hcurB, const float* __restrict__ hcurF,
    const __bf16* __restrict__ wlds, const GiReg& gi,
    float bh0, float bh1, float bh2,
    float* __restrict__ hnF, __bf16* __restrict__ hnB,
    float* __restrict__ yencD_tt,     // yenc_dir + tt*HD ([b][t][c]) or null
    __bf16* __restrict__ zrow,        // Zb + s*BB*KZ or null
    int c0, int lane, int w)
{
    const int r16 = lane & 15, hi = lane >> 4;
    const int c = c0 + r16;
    const int brow = 16 * w;

    // batched independent sc1 loads: 28 A-fragments + 4 h_prev scalars
    bf16x8 afr[28];
    const __bf16* ap = hcurB + (size_t)(brow + r16) * HD + hi * 8;
#pragma unroll
    for (int kk = 0; kk < 28; ++kk) afr[kk] = ld128_sc(ap + kk * 32);
    const float* hpp = hcurF + (size_t)(brow + hi * 4) * HD + c;
    const float hp0 = ldf_sc(hpp);
    const float hp1 = ldf_sc(hpp + HD);
    const float hp2 = ldf_sc(hpp + 2 * HD);
    const float hp3 = ldf_sc(hpp + 3 * HD);
    vm_wait0();
    __builtin_amdgcn_sched_barrier(0);

    f32x4 a0 = {0.f, 0.f, 0.f, 0.f}, a1 = a0, a2 = a0;
#pragma unroll
    for (int kk = 0; kk < 28; ++kk) {
        const bf16x8 b0 = *(const bf16x8*)&wlds[(kk) * 512 + lane * 8];
        const bf16x8 b1 = *(const bf16x8*)&wlds[(28 + kk) * 512 + lane * 8];
        const bf16x8 b2 = *(const bf16x8*)&wlds[(56 + kk) * 512 + lane * 8];
        a0 = __builtin_amdgcn_mfma_f32_16x16x32_bf16(afr[kk], b0, a0, 0, 0, 0);
        a1 = __builtin_amdgcn_mfma_f32_16x16x32_bf16(afr[kk], b1, a1, 0, 0, 0);
        a2 = __builtin_amdgcn_mfma_f32_16x16x32_bf16(afr[kk], b2, a2, 0, 0, 0);
    }

    const float hpv[4] = {hp0, hp1, hp2, hp3};
#pragma unroll
    for (int rg = 0; rg < 4; ++rg) {
        const int b = brow + hi * 4 + rg;
        const float rr = sig_(gi.g0[rg] + a0[rg] + bh0);
        const float zz = sig_(gi.g1[rg] + a1[rg] + bh1);
        const float nn = tanh_(gi.g2[rg] + rr * (a2[rg] + bh2));
        const float hnew = (1.0f - zz) * nn + zz * hpv[rg];
        stf_sc(hnF + (size_t)b * HD + c, hnew);
        sth_sc(hnB + (size_t)b * HD + c, hnew);
        if (yencD_tt) stf_sc(yencD_tt + (size_t)b * TE * HD + c, hnew);  // sc1: read via sc1 later
        if (zrow)    zrow[(size_t)b * KZ + c] = (__bf16)hnew;  // plain: post-kernel consumer
    }
}

// attention for one batch element b; posts its flag right after the h2 reads
// are done (frees the h-slot for the GRU ring), then computes from LDS only.
__device__ __forceinline__ void attn_step(
    const float* __restrict__ yencL, float* __restrict__ h2s,
    float* __restrict__ scL, float* __restrict__ attwL,
    const float* __restrict__ h2g, int b, __bf16* __restrict__ zr,
    int* __restrict__ myflag, int postval)
{
    const int tid = threadIdx.x, lane = tid & 63, w = tid >> 6;

    const float* hb_ = h2g + (size_t)b * HD;
    const float a0 = ldf_sc(hb_ + tid);
    const float a1 = ldf_sc(hb_ + tid + 256);
    const float a2 = ldf_sc(hb_ + tid + 512);
    const float a3 = (tid < HD - 768) ? ldf_sc(hb_ + tid + 768) : 0.0f;
    vm_wait0();
    __builtin_amdgcn_sched_barrier(0);
    h2s[tid] = a0; h2s[tid + 256] = a1; h2s[tid + 512] = a2;
    if (tid < HD - 768) h2s[tid + 768] = a3;
    __syncthreads();
    if (tid == 0) sti_sc(myflag, postval);   // h-slot reads complete -> release

    const float2* h22 = (const float2*)h2s;
    for (int t = w; t < TE; t += 4) {
        const float2* y2 = (const float2*)(yencL + t * HD);
        float p = 0.f;
#pragma unroll
        for (int it = 0; it < HD / 128; ++it) {
            const float2 ya = y2[lane + it * 64];
            const float2 hb2 = h22[lane + it * 64];
            p += ya.x * hb2.x + ya.y * hb2.y;
        }
        p += __shfl_down(p, 32); p += __shfl_down(p, 16); p += __shfl_down(p, 8);
        p += __shfl_down(p, 4);  p += __shfl_down(p, 2);  p += __shfl_down(p, 1);
        if (lane == 0) scL[t] = p;
    }
    __syncthreads();

    float m = scL[0];
    for (int t = 1; t < TE; ++t) m = fmaxf(m, scL[t]);
    float s = 0.f;
    for (int t = 0; t < TE; ++t) s += __expf(scL[t] - m);
    const float inv = 1.0f / s;
    if (tid < TE) attwL[tid] = __expf(scL[tid] - m) * inv;
    __syncthreads();

    for (int c = tid; c < HD; c += 256) {
        float acc = 0.f;
#pragma unroll
        for (int t = 0; t < TE; ++t) acc += attwL[t] * yencL[t * HD + c];
        zr[(size_t)b * KZ + HD + c] = (__bf16)acc;   // plain: post-kernel consumer
    }
    __syncthreads();
}

// ---------------------------------------------------------------------------
// Persistent recurrence kernel with distributed flag synchronization.
// Encoder: blocks 0..55 fwd GRU, 56..111 bwd GRU (decoupled chains), 112..119 idle.
// Decoder: blocks 0..55 GRU (h ring of 4); blocks 56..119 attention (b=gid-56).
// ---------------------------------------------------------------------------
__global__ __launch_bounds__(256, 1) void recur(
    const float* __restrict__ GIf, const float* __restrict__ GIb,
    const float* __restrict__ GId,
    const float* __restrict__ WhhF, const float* __restrict__ WhhB,
    const float* __restrict__ WhhD,
    const float* __restrict__ bhhF, const float* __restrict__ bhhB,
    const float* __restrict__ bhhD,
    float* __restrict__ heF, __bf16* __restrict__ heB,   // [dir][2][S]
    float* __restrict__ hdF, __bf16* __restrict__ hdB,   // [4][S] ring
    float* __restrict__ yenc_f, float* __restrict__ yenc_b,  // [b][t][c]
    __bf16* __restrict__ Zb, int* __restrict__ flags)
{
    __shared__ __align__(16) char smem[147456];
    __bf16* wlds  = (__bf16*)smem;                 // gru role: 3*28*64*8 bf16 (86,016 B)
    float*  yencL = (float*)smem;                  // attn role: [40][896] f32 (143,360 B)
    float*  h2s   = (float*)(smem + 143360);       // [896]
    float*  scL   = (float*)(smem + 146944);       // [40]
    float*  attwL = (float*)(smem + 147136);       // [40]

    const int gid = blockIdx.x;
    const int tid = threadIdx.x;
    const int lane = tid & 63, w = tid >> 6;
    const int r16 = lane & 15, hi = lane >> 4;
    const size_t S = (size_t)BB * HD;

    float bb0 = 0.f, bb1 = 0.f, bb2 = 0.f;
    GiReg gi;

    // ================= encoder =================
    if (gid < 112) {
        const int dir = (gid >= 56) ? 1 : 0;
        const int gloc = dir ? gid - 56 : gid;
        const int c0e = gloc * 16;
        const float* GIe  = dir ? GIb : GIf;
        const float* bhhE = dir ? bhhB : bhhF;
        float* yencD = dir ? yenc_b : yenc_f;
        const int foff = dir ? BOFF : FOFF;

        stage_w(wlds, dir ? WhhB : WhhF, c0e);
        const int ce = c0e + r16;
        bb0 = bhhE[ce]; bb1 = bhhE[HD + ce]; bb2 = bhhE[2 * HD + ce];
        gi = gi_prefetch(GIe + (size_t)(dir ? TE - 1 : 0) * BB * G3, ce, w, hi);
        __syncthreads();

        for (int t = 0; t < TE; ++t) {
            if (t > 0) {
                if (tid < 56) spin_ge(flags + foff + tid, t);
                __syncthreads();
            }
            const int tt = dir ? (TE - 1 - t) : t;
            gru_step(heB + (dir * 2 + (t & 1)) * S, heF + (dir * 2 + (t & 1)) * S,
                     wlds, gi, bb0, bb1, bb2,
                     heF + (dir * 2 + ((t + 1) & 1)) * S, heB + (dir * 2 + ((t + 1) & 1)) * S,
                     yencD + (size_t)tt * HD, nullptr, c0e, lane, w);
            if (t + 1 < TE) {
                const int ttn = dir ? (TE - 2 - t) : (t + 1);
                gi = gi_prefetch(GIe + (size_t)ttn * BB * G3, ce, w, hi);
            }
            vm_wait0();
            __syncthreads();
            if (tid == 0) sti_sc(flags + foff + gloc, t + 1);
        }
    }

    // ================= transition =================
    // wait all encoder chains done (F and B regions are contiguous)
    if (tid < 112) spin_ge(flags + tid, TE);
    __syncthreads();

    {   // hd slot0 = hf + hb (sc1), cooperatively across all 120 blocks
        const int i0 = gid * 256 + tid;
        const int i1 = i0 + NBLK * 256;
        const bool has1 = (i1 < BB * HD);
        const float f0 = ldf_sc(&heF[0 * S + i0]);
        const float b0 = ldf_sc(&heF[2 * S + i0]);
        const float f1 = has1 ? ldf_sc(&heF[0 * S + i1]) : 0.f;
        const float b1 = has1 ? ldf_sc(&heF[2 * S + i1]) : 0.f;
        vm_wait0();
        __builtin_amdgcn_sched_barrier(0);
        const float v0 = f0 + b0;
        stf_sc(&hdF[i0], v0); sth_sc(&hdB[i0], v0);
        if (has1) { const float v1 = f1 + b1; stf_sc(&hdF[i1], v1); sth_sc(&hdB[i1], v1); }
    }
    if (gid < 56) {   // restage decoder weights while hd stores drain
        stage_w(wlds, WhhD, gid * 16);
        const int cd = gid * 16 + r16;
        bb0 = bhhD[cd]; bb1 = bhhD[HD + cd]; bb2 = bhhD[2 * HD + cd];
        gi = gi_prefetch(GId, cd, w, hi);
    }
    vm_wait0();
    __syncthreads();
    if (tid == 0) sti_sc(flags + TOFF + gid, 1);
    if (tid < 120) spin_ge(flags + TOFF + tid, 1);
    __syncthreads();

    // ================= decoder =================
    if (gid < 56) {
        // GRU chain: waits only its 56 peers + lagging-attn buffer protect
        for (int p = 0; p < TD; ++p) {
            if (p > 0 && tid < 56) spin_ge(flags + DOFF + tid, p);
            if (p >= 4 && tid >= 64 && tid < 128) spin_ge(flags + AOFF + (tid - 64), p - 3);
            __syncthreads();
            gru_step(hdB + (size_t)(p & 3) * S, hdF + (size_t)(p & 3) * S,
                     wlds, gi, bb0, bb1, bb2,
                     hdF + (size_t)((p + 1) & 3) * S, hdB + (size_t)((p + 1) & 3) * S,
                     nullptr, Zb + (size_t)p * BB * KZ, gid * 16, lane, w);
            if (p + 1 < TD)
                gi = gi_prefetch(GId + (size_t)(p + 1) * BB * G3, gid * 16 + r16, w, hi);
            vm_wait0();
            __syncthreads();
            if (tid == 0) sti_sc(flags + DOFF + gid, p + 1);
        }
    } else {
        const int b = gid - 56;
        // stage yencL = yenc_f[b] + yenc_b[b] via sc1 (5-deep batched loads)
        const float* sf = yenc_f + (size_t)b * TE * HD;
        const float* sb = yenc_b + (size_t)b * TE * HD;
        for (int it = 0; it < 7; ++it) {
            const int i = it * 1280 + tid;   // 5 float4s per thread per iter
            f32x4 a_[5], b_[5];
#pragma unroll
            for (int u = 0; u < 5; ++u) {
                a_[u] = ldf4_sc(sf + (size_t)(i + u * 256) * 4);
                b_[u] = ldf4_sc(sb + (size_t)(i + u * 256) * 4);
            }
            vm_wait0();
            __builtin_amdgcn_sched_barrier(0);
#pragma unroll
            for (int u = 0; u < 5; ++u)
                *(f32x4*)&yencL[(size_t)(i + u * 256) * 4] = a_[u] + b_[u];
        }
        __syncthreads();
        for (int s = 0; s < TD; ++s) {
            if (tid < 56) spin_ge(flags + DOFF + tid, s + 1);
            __syncthreads();
            attn_step(yencL, h2s, scL, attwL, hdF + (size_t)((s + 1) & 3) * S,
                      b, Zb + (size_t)s * BB * KZ, flags + AOFF + b, s + 1);
        }
    }
}

// ---------------------------------------------------------------------------
// bf16 MFMA GEMM, C = A @ B^T (+bias), M-major order + bijective XCD swizzle.
// MODE 0: C[M][N]. MODE 1: FC epilogue into d_out layout.
// ---------------------------------------------------------------------------
template<int BM, int BN, int WGM, int WGN, int MODE>
__global__ __launch_bounds__(256) void gemm_bt(
    const __bf16* __restrict__ A0, const __bf16* __restrict__ B0,
    float* __restrict__ C0, const float* __restrict__ bias0,
    const __bf16* __restrict__ A1, const __bf16* __restrict__ B1,
    float* __restrict__ C1, const float* __restrict__ bias1,
    int M, int N, int K, int Nreal)
{
    constexpr int BK = 32, PAD = 8;
    constexpr int WM = BM / WGM, WN = BN / WGN;
    constexpr int FM = WM / 16, FN = WN / 16;
    constexpr int LDS_W = BK + PAD;

    const __bf16* A = A0; const __bf16* Bp = B0;
    float* C = C0; const float* bias = bias0;
    if (blockIdx.z == 1) { A = A1; Bp = B1; C = C1; bias = bias1; }

    __shared__ __bf16 Ash[BM][LDS_W];
    __shared__ __bf16 Bsh[BN][LDS_W];

    const int tid  = threadIdx.x;
    const int lane = tid & 63;
    const int wave = tid >> 6;
    const int wr = wave / WGN, wc = wave % WGN;

    const int nwg = gridDim.x * gridDim.y;
    const int orig = blockIdx.y * gridDim.x + blockIdx.x;
    const int q = nwg >> 3, r = nwg & 7;
    const int xcd = orig & 7, idx = orig >> 3;
    const int wg = (xcd < r ? xcd * (q + 1) : r * (q + 1) + (xcd - r) * q) + idx;
    const int mtiles = gridDim.y;
    const long tileM = (long)(wg % mtiles) * BM;
    const long tileN = (long)(wg / mtiles) * BN;

    const int r16 = lane & 15;
    const int hi  = lane >> 4;

    f32x4 acc[FM][FN];
    const f32x4 zero = {0.f, 0.f, 0.f, 0.f};
#pragma unroll
    for (int m = 0; m < FM; ++m)
#pragma unroll
        for (int n = 0; n < FN; ++n) acc[m][n] = zero;

    for (int k0 = 0; k0 < K; k0 += BK) {
#pragma unroll
        for (int it = 0; it < (BM * 4) / 256; ++it) {
            int id = it * 256 + tid;
            int rr = id >> 2, cv = (id & 3) << 3;
            *(u32x4*)&Ash[rr][cv] = *(const u32x4*)&A[(tileM + rr) * K + k0 + cv];
        }
#pragma unroll
        for (int it = 0; it < (BN * 4) / 256; ++it) {
            int id = it * 256 + tid;
            int rr = id >> 2, cv = (id & 3) << 3;
            *(u32x4*)&Bsh[rr][cv] = *(const u32x4*)&Bp[(tileN + rr) * K + k0 + cv];
        }
        __syncthreads();

        bf16x8 af[FM], bfr[FN];
#pragma unroll
        for (int m = 0; m < FM; ++m)
            af[m] = *(const bf16x8*)&Ash[wr * WM + m * 16 + r16][hi * 8];
#pragma unroll
        for (int n = 0; n < FN; ++n)
            bfr[n] = *(const bf16x8*)&Bsh[wc * WN + n * 16 + r16][hi * 8];
#pragma unroll
        for (int m = 0; m < FM; ++m)
#pragma unroll
            for (int n = 0; n < FN; ++n)
                acc[m][n] = __builtin_amdgcn_mfma_f32_16x16x32_bf16(af[m], bfr[n], acc[m][n], 0, 0, 0);
        __syncthreads();
    }

#pragma unroll
    for (int m = 0; m < FM; ++m) {
#pragma unroll
        for (int n = 0; n < FN; ++n) {
            const long gcol = tileN + wc * WN + n * 16 + r16;
            if (MODE == 1 && gcol >= Nreal) continue;
            const float bv = bias ? bias[gcol] : 0.0f;
#pragma unroll
            for (int rr = 0; rr < 4; ++rr) {
                const long grow = tileM + wr * WM + m * 16 + hi * 4 + rr;
                const float v = acc[m][n][rr] + bv;
                if (MODE == 0) {
                    C[grow * N + gcol] = v;
                } else {
                    const long t = grow >> 6, b = grow & 63;
                    C[(b * TD + t) * VO + gcol] = v;
                }
            }
        }
    }
}

// fp32 -> bf16 convert with row/col zero-padding
__global__ __launch_bounds__(256) void conv_pad(const float* __restrict__ src,
                                                __bf16* __restrict__ dst,
                                                int Rout, int Rin, int Kout, int Kin)
{
    size_t i = (size_t)blockIdx.x * 256 + threadIdx.x;
    const size_t total = (size_t)Rout * Kout;
    const size_t stride = (size_t)gridDim.x * 256;
    for (; i < total; i += stride) {
        int k = (int)(i % Kout);
        int r = (int)(i / Kout);
        float v = (r < Rin && k < Kin) ? src[(size_t)r * Kin + k] : 0.0f;
        dst[i] = (__bf16)v;
    }
}

// gather token embeddings into padded bf16 matrix X[(t*B+b)][EP]
__global__ __launch_bounds__(256) void gather_embed(const int* __restrict__ tok,
                                                    const float* __restrict__ emb,
                                                    __bf16* __restrict__ X)
{
    int i = blockIdx.x * 256 + threadIdx.x;
    const int total = TE * BB * EP;
    for (; i < total; i += gridDim.x * 256) {
        int e = i % EP;
        int row = i / EP;
        int t = row >> 6, b = row & 63;
        float v = 0.0f;
        if (e < ED) v = emb[(size_t)tok[b * TE + t] * ED + e];
        X[i] = (__bf16)v;
    }
}

// LDS-staged row softmax: 1 HBM read + 1 HBM write
__global__ __launch_bounds__(256) void softmax_kernel(float* __restrict__ out)
{
    __shared__ float row[VO];
    __shared__ float red[4];
    const size_t base = (size_t)blockIdx.x * VO;
    const int tid = threadIdx.x;

    float m = -1e30f;
    for (int ch = tid; ch < VO / 4; ch += 256) {
        const float4 x = *(const float4*)&out[base + ch * 4];
        *(float4*)&row[ch * 4] = x;
        m = fmaxf(fmaxf(fmaxf(m, x.x), x.y), fmaxf(x.z, x.w));
    }
    m = fmaxf(m, __shfl_down(m, 32)); m = fmaxf(m, __shfl_down(m, 16));
    m = fmaxf(m, __shfl_down(m, 8));  m = fmaxf(m, __shfl_down(m, 4));
    m = fmaxf(m, __shfl_down(m, 2));  m = fmaxf(m, __shfl_down(m, 1));
    if ((tid & 63) == 0) red[tid >> 6] = m;
    __syncthreads();
    m = fmaxf(fmaxf(red[0], red[1]), fmaxf(red[2], red[3]));

    float s = 0.0f;
    for (int v = tid; v < VO; v += 256) s += __expf(row[v] - m);
    s += __shfl_down(s, 32); s += __shfl_down(s, 16); s += __shfl_down(s, 8);
    s += __shfl_down(s, 4);  s += __shfl_down(s, 2);  s += __shfl_down(s, 1);
    __syncthreads();
    if ((tid & 63) == 0) red[tid >> 6] = s;
    __syncthreads();
    s = red[0] + red[1] + red[2] + red[3];

    const float inv = 1.0f / s;
    for (int ch = tid; ch < VO / 4; ch += 256) {
        float4 x = *(const float4*)&row[ch * 4];
        x.x = __expf(x.x - m) * inv;
        x.y = __expf(x.y - m) * inv;
        x.z = __expf(x.z - m) * inv;
        x.w = __expf(x.w - m) * inv;
        *(float4*)&out[base + ch * 4] = x;
    }
}

extern "C" void kernel_launch(void* const* d_in, const int* in_sizes, int n_in,
                              void* d_out, int out_size, void* d_ws, size_t ws_size,
                              hipStream_t stream)
{
    if (n_in < 18) return;
    const int*   x_enc   = (const int*)d_in[0];
    const int*   x_dec   = (const int*)d_in[1];
    const float* emb_enc = (const float*)d_in[2];
    const float* Wih_f   = (const float*)d_in[3];
    const float* Whh_f   = (const float*)d_in[4];
    const float* bih_f   = (const float*)d_in[5];
    const float* bhh_f   = (const float*)d_in[6];
    const float* Wih_b   = (const float*)d_in[7];
    const float* Whh_b   = (const float*)d_in[8];
    const float* bih_b   = (const float*)d_in[9];
    const float* bhh_b   = (const float*)d_in[10];
    const float* emb_dec = (const float*)d_in[11];
    const float* Wih_d   = (const float*)d_in[12];
    const float* Whh_d   = (const float*)d_in[13];
    const float* bih_d   = (const float*)d_in[14];
    const float* bhh_d   = (const float*)d_in[15];
    const float* fc_W    = (const float*)d_in[16];
    const float* fc_b    = (const float*)d_in[17];
    float* out = (float*)d_out;

    size_t off = 0;
    auto alloc = [&](size_t bytes) -> void* {
        void* p = (char*)d_ws + off;
        off = (off + bytes + 255) & ~(size_t)255;
        return p;
    };
    __bf16* fcWb   = (__bf16*)alloc((size_t)VP * KZ * 2);
    __bf16* WihFb  = (__bf16*)alloc((size_t)G3 * EP * 2);
    __bf16* WihBb  = (__bf16*)alloc((size_t)G3 * EP * 2);
    __bf16* WihDb  = (__bf16*)alloc((size_t)G3 * EP * 2);
    __bf16* Xe     = (__bf16*)alloc((size_t)MR * EP * 2);
    __bf16* Xd     = (__bf16*)alloc((size_t)MR * EP * 2);
    float*  GIf    = (float*)alloc((size_t)MR * G3 * 4);
    float*  GIb    = (float*)alloc((size_t)MR * G3 * 4);
    float*  GId    = (float*)alloc((size_t)MR * G3 * 4);
    __bf16* Zb     = (__bf16*)alloc((size_t)MR * KZ * 2);
    float*  yenc_f = (float*)alloc((size_t)BB * TE * HD * 4);
    float*  yenc_b = (float*)alloc((size_t)BB * TE * HD * 4);
    float*  hdF    = (float*)alloc((size_t)4 * BB * HD * 4);   // ring of 4
    __bf16* hdB    = (__bf16*)alloc((size_t)4 * BB * HD * 2);
    char* zero_start = (char*)d_ws + off;
    float*  heF    = (float*)alloc((size_t)4 * BB * HD * 4);   // [dir][buf]
    __bf16* heB    = (__bf16*)alloc((size_t)4 * BB * HD * 2);
    int*    flags  = (int*)alloc(512 * 4);
    size_t zero_bytes = (size_t)(((char*)d_ws + off) - zero_start);
    if (off > ws_size) return;   // ~230 MB required; fail visibly (zero output)

    // ---- init + weight conversion + embedding gather ----
    hipMemsetAsync(zero_start, 0, zero_bytes, stream);
    conv_pad<<<8192, 256, 0, stream>>>(fc_W,  fcWb,  VP, VO, KZ, KZ);
    conv_pad<<<3360, 256, 0, stream>>>(Wih_f, WihFb, G3, G3, EP, ED);
    conv_pad<<<3360, 256, 0, stream>>>(Wih_b, WihBb, G3, G3, EP, ED);
    conv_pad<<<3360, 256, 0, stream>>>(Wih_d, WihDb, G3, G3, EP, ED);
    gather_embed<<<3200, 256, 0, stream>>>(x_enc, emb_enc, Xe);
    gather_embed<<<3200, 256, 0, stream>>>(x_dec, emb_dec, Xd);

    // ---- batched input-side GEMMs: GI = X @ Wih^T + bih ----
    gemm_bt<128, 128, 2, 2, 0><<<dim3(G3 / 128, MR / 128, 2), 256, 0, stream>>>(
        Xe, WihFb, GIf, bih_f, Xe, WihBb, GIb, bih_b, MR, G3, EP, G3);
    gemm_bt<128, 128, 2, 2, 0><<<dim3(G3 / 128, MR / 128, 1), 256, 0, stream>>>(
        Xd, WihDb, GId, bih_d, nullptr, nullptr, nullptr, nullptr, MR, G3, EP, G3);

    // ---- persistent recurrence: encoder + decoder + attention ----
    recur<<<NBLK, 256, 0, stream>>>(GIf, GIb, GId, Whh_f, Whh_b, Whh_d,
                                    bhh_f, bhh_b, bhh_d,
                                    heF, heB, hdF, hdB, yenc_f, yenc_b, Zb, flags);

    // ---- batched FC: logits = Z @ fc_W^T + fc_b -> d_out ----
    gemm_bt<128, 128, 2, 2, 1><<<dim3(VP / 128, MR / 128, 1), 256, 0, stream>>>(
        Zb, fcWb, out, fc_b, nullptr, nullptr, nullptr, nullptr, MR, VP, KZ, VO);

    // ---- in-place row softmax ----
    softmax_kernel<<<BB * TD, 256, 0, stream>>>(out);
}